// Round 5
// baseline (64665.387 us; speedup 1.0000x reference)
//
#include <hip/hip_runtime.h>
#include <cstdint>
#include <cstddef>

constexpr int NN = 2048;

// ---------------- diagnostic fill ----------------
__global__ void fill_k(float* __restrict__ o, float v, size_t ntot) {
  size_t i = (size_t)blockIdx.x * 256 + threadIdx.x;
  if (i < ntot) o[i] = v;
}

// ---------------- prep kernels (all fp32) ----------------

// AT[m][n] = A[n][m]
__global__ void prep_AT_k(const float* __restrict__ A, float* __restrict__ AT) {
  int tid = blockIdx.x * 256 + threadIdx.x;   // 2048*2048
  int n = tid & 2047, m = tid >> 11;
  AT[(size_t)m * NN + n] = A[(size_t)n * NN + m];
}

// WT[(d*192 + k*64 + i)*CO + o] = Wp[((d*3+k)*66+i)*CO + o], i<64 (h-part)
template<int CO>
__global__ void prep_wt_k(const float* __restrict__ Wp, float* __restrict__ WT) {
  int tid = blockIdx.x * 256 + threadIdx.x;   // 1920*CO
  int o = tid & (CO - 1), j = tid / CO;
  int d = j / 192, rem = j - d * 192;
  int k = rem >> 6, i = rem & 63;
  WT[tid] = Wp[((size_t)((d * 3 + k) * 66 + i)) * CO + o];
}

// Wx[n][t6 = k*2+ii][o] = sum_d E[n,d]*Wp[((d*3+k)*66+64+ii)*CO+o]
template<int CO>
__global__ void prep_wx_k(const float* __restrict__ E, const float* __restrict__ Wp,
                          float* __restrict__ Wx) {
  int tid = blockIdx.x * 256 + threadIdx.x;   // 2048*6*CO
  int o = tid & (CO - 1), t6 = (tid / CO) % 6, n = tid / (6 * CO);
  int k = t6 >> 1, ii = t6 & 1;
  float s = 0.f;
  for (int d = 0; d < 10; ++d)
    s += E[n * 10 + d] * Wp[((size_t)((d * 3 + k) * 66 + 64 + ii)) * CO + o];
  Wx[tid] = s;
}

template<int CO>
__global__ void prep_b_k(const float* __restrict__ E, const float* __restrict__ bp,
                         float* __restrict__ bv) {
  int tid = blockIdx.x * 256 + threadIdx.x;   // 2048*CO
  int o = tid & (CO - 1), n = tid / CO;
  float s = 0.f;
  for (int d = 0; d < 10; ++d) s += E[n * 10 + d] * bp[d * CO + o];
  bv[tid] = s;
}

// X0t[c = (lt*16+b)*2+ii][n] = x[b][lt][n][ii]
__global__ void prep_x0_k(const float* __restrict__ x, float* __restrict__ X0t) {
  int tid = blockIdx.x * 256 + threadIdx.x;   // 384*2048
  int n = tid & 2047, c = tid >> 11;
  int ii = c & 1, b = (c >> 1) & 15, lt = c >> 5;
  X0t[(size_t)c * NN + n] = x[(((size_t)(b * 12 + lt)) * NN + n) * 2 + ii];
}

// ---------------- fp32 SpMM: Out[c][n] = sum_m In[c][m] * AT[m][n] ----------------
// grid (16, C/32), block 128; thread owns one n and 32 c-accumulators.
__global__ __launch_bounds__(128) void spmm_k(const float* __restrict__ In,
                                              const float* __restrict__ AT,
                                              float* __restrict__ Out) {
  const int n = blockIdx.x * 128 + threadIdx.x;
  const int c0 = blockIdx.y * 32;
  float acc[32];
#pragma unroll
  for (int i = 0; i < 32; ++i) acc[i] = 0.f;
  for (int m = 0; m < NN; ++m) {
    const float a = AT[(size_t)m * NN + n];
#pragma unroll
    for (int cc = 0; cc < 32; ++cc)
      acc[cc] += In[(size_t)(c0 + cc) * NN + m] * a;
  }
#pragma unroll
  for (int cc = 0; cc < 32; ++cc)
    Out[(size_t)(c0 + cc) * NN + n] = acc[cc];
}

// ---------------- gate: stage 16x192 tile, K=1920 pool-factored GEMM, epilogue ----------------
// writes rh -> RHt (feature-major) and u -> ubuf. grid NB*2048/16, block 128 (=o).
__global__ __launch_bounds__(128) void gate_k(
    const float* __restrict__ Y1t, const float* __restrict__ Y2t,
    const float* __restrict__ Hs, const float* __restrict__ WT,
    const float* __restrict__ E, const float* __restrict__ bgv,
    const float* __restrict__ Wx, const float* __restrict__ x,
    const float* __restrict__ X1t, const float* __restrict__ X2t,
    float* __restrict__ RHt, float* __restrict__ ubuf, int lt, int b0) {
  const int R0 = blockIdx.x * 16;
  const int bl = R0 >> 11, n0 = R0 & 2047;   // local b (0..7), node base
  __shared__ float xr[16][192];
  const int tid = threadIdx.x;
  {
    const int rr = tid >> 3, q = tid & 7;
    for (int jj = 0; jj < 8; ++jj) {
      const int j = jj * 8 + q;
      const float h = Hs[(size_t)(R0 + rr) * 64 + j];
      xr[rr][j] = h;                                                     // k0: h
      xr[rr][64 + j]  = Y1t[(size_t)(bl * 64 + j) * NN + n0 + rr];       // k1: A@h
      xr[rr][128 + j] = 2.f * Y2t[(size_t)(bl * 64 + j) * NN + n0 + rr] - h; // k2
    }
  }
  __syncthreads();
  const int o = tid;
  float acc[16];
#pragma unroll
  for (int rr = 0; rr < 16; ++rr) acc[rr] = 0.f;
  for (int d = 0; d < 10; ++d) {
    float tmp[16];
#pragma unroll
    for (int rr = 0; rr < 16; ++rr) tmp[rr] = 0.f;
    for (int j = 0; j < 192; ++j) {
      const float w = WT[(size_t)(d * 192 + j) * 128 + o];
#pragma unroll
      for (int rr = 0; rr < 16; ++rr) tmp[rr] += xr[rr][j] * w;
    }
#pragma unroll
    for (int rr = 0; rr < 16; ++rr)
      acc[rr] += E[(n0 + rr) * 10 + d] * tmp[rr];
  }
  const int gb = b0 + bl;
  const size_t xbase = ((size_t)(gb * 12 + lt)) * NN;
  const size_t c1 = ((size_t)(lt * 16 + gb)) * 2;
  for (int rr = 0; rr < 16; ++rr) {
    const int n = n0 + rr;
    const size_t R = (size_t)R0 + rr;
    const float x0a = x[(xbase + n) * 2 + 0];
    const float x0b = x[(xbase + n) * 2 + 1];
    const float x1a = X1t[c1 * NN + n];
    const float x1b = X1t[(c1 + 1) * NN + n];
    const float x2a = 2.f * X2t[c1 * NN + n] - x0a;
    const float x2b = 2.f * X2t[(c1 + 1) * NN + n] - x0b;
    const float* wx = Wx + (size_t)n * 768;
    float pre = acc[rr] + bgv[(size_t)n * 128 + o]
              + x0a * wx[o]       + x0b * wx[128 + o]
              + x1a * wx[256 + o] + x1b * wx[384 + o]
              + x2a * wx[512 + o] + x2b * wx[640 + o];
    const float g = 1.f / (1.f + expf(-pre));
    if (o < 64) {
      RHt[(size_t)(bl * 64 + o) * NN + n] = g * Hs[R * 64 + o];  // r*h
    } else {
      ubuf[R * 64 + (o - 64)] = g;                                // u
    }
  }
}

// ---------------- cand: stage 16x192 (rh, A@rh, 2AA@rh - rh), GEMM, GRU update ----------------
// block 128: o = tid&63, hh = tid>>6 handles 8 rows each.
__global__ __launch_bounds__(128) void cand_k(
    const float* __restrict__ Y1t, const float* __restrict__ Y2t,
    const float* __restrict__ RHt, const float* __restrict__ WT,
    const float* __restrict__ E, const float* __restrict__ bcv,
    const float* __restrict__ Wx, const float* __restrict__ x,
    const float* __restrict__ X1t, const float* __restrict__ X2t,
    const float* __restrict__ ubuf, float* __restrict__ Hs,
    float* __restrict__ Ht, float* __restrict__ out, int lt, int b0) {
  const int R0 = blockIdx.x * 16;
  const int bl = R0 >> 11, n0 = R0 & 2047;
  __shared__ float xr[16][192];
  const int tid = threadIdx.x;
  {
    const int rr = tid >> 3, q = tid & 7;
    for (int jj = 0; jj < 8; ++jj) {
      const int j = jj * 8 + q;
      const float rh = RHt[(size_t)(bl * 64 + j) * NN + n0 + rr];
      xr[rr][j] = rh;
      xr[rr][64 + j]  = Y1t[(size_t)(bl * 64 + j) * NN + n0 + rr];
      xr[rr][128 + j] = 2.f * Y2t[(size_t)(bl * 64 + j) * NN + n0 + rr] - rh;
    }
  }
  __syncthreads();
  const int o = tid & 63, hh = tid >> 6;
  float acc[8];
#pragma unroll
  for (int r8 = 0; r8 < 8; ++r8) acc[r8] = 0.f;
  for (int d = 0; d < 10; ++d) {
    float tmp[8];
#pragma unroll
    for (int r8 = 0; r8 < 8; ++r8) tmp[r8] = 0.f;
    for (int j = 0; j < 192; ++j) {
      const float w = WT[(size_t)(d * 192 + j) * 64 + o];
#pragma unroll
      for (int r8 = 0; r8 < 8; ++r8) tmp[r8] += xr[hh * 8 + r8][j] * w;
    }
#pragma unroll
    for (int r8 = 0; r8 < 8; ++r8)
      acc[r8] += E[(n0 + hh * 8 + r8) * 10 + d] * tmp[r8];
  }
  const int gb = b0 + bl;
  const size_t xbase = ((size_t)(gb * 12 + lt)) * NN;
  const size_t c1 = ((size_t)(lt * 16 + gb)) * 2;
  for (int r8 = 0; r8 < 8; ++r8) {
    const int rr = hh * 8 + r8;
    const int n = n0 + rr;
    const size_t R = (size_t)R0 + rr;
    const float x0a = x[(xbase + n) * 2 + 0];
    const float x0b = x[(xbase + n) * 2 + 1];
    const float x1a = X1t[c1 * NN + n];
    const float x1b = X1t[(c1 + 1) * NN + n];
    const float x2a = 2.f * X2t[c1 * NN + n] - x0a;
    const float x2b = 2.f * X2t[(c1 + 1) * NN + n] - x0b;
    const float* wx = Wx + (size_t)n * 384;
    float pre = acc[r8] + bcv[(size_t)n * 64 + o]
              + x0a * wx[o]       + x0b * wx[64 + o]
              + x1a * wx[128 + o] + x1b * wx[192 + o]
              + x2a * wx[256 + o] + x2b * wx[320 + o];
    const float cv = tanhf(pre);
    const float u = ubuf[R * 64 + o];
    const float hold = Hs[R * 64 + o];
    const float hn = u * hold + (1.f - u) * cv;
    Hs[R * 64 + o] = hn;
    out[(xbase + n) * 64 + o] = hn;
    Ht[(size_t)(bl * 64 + o) * NN + n] = hn;
  }
}

// ---------------- launch ----------------
extern "C" void kernel_launch(void* const* d_in, const int* in_sizes, int n_in,
                              void* d_out, int out_size, void* d_ws, size_t ws_size,
                              hipStream_t stream) {
  float* out = (float*)d_out;

  // guard 1: input layout must match the reference
  const bool in_ok = (n_in == 7) &&
      in_sizes[0] == 786432 && in_sizes[1] == 20480 && in_sizes[2] == 4194304 &&
      in_sizes[3] == 253440 && in_sizes[4] == 1280 &&
      in_sizes[5] == 126720 && in_sizes[6] == 640 && out_size == 27262976;
  if (!in_ok) {
    fill_k<<<(out_size + 255) / 256, 256, 0, stream>>>(out, 77.0f, (size_t)out_size);
    return;
  }
  // guard 2: workspace must fit the carve plan
  constexpr size_t NEED = 60719104;
  if (ws_size < NEED) {
    fill_k<<<106496, 256, 0, stream>>>(out, 42.0f, 27262976);
    return;
  }

  const float* x   = (const float*)d_in[0];
  const float* E   = (const float*)d_in[1];
  const float* A   = (const float*)d_in[2];
  const float* Wgp = (const float*)d_in[3];
  const float* bgp = (const float*)d_in[4];
  const float* Wcp = (const float*)d_in[5];
  const float* bcp = (const float*)d_in[6];

  char* p = (char*)d_ws;
  auto carve = [&](size_t bytes) { char* r = p; p += bytes; return r; };
  float* AT  = (float*)carve(16777216);   // A^T [2048 m][2048 n]
  float* X1t = (float*)carve(3145728);    // A@x    [384][2048]
  float* X2t = (float*)carve(3145728);    // A@A@x  [384][2048]
  float* WgT = (float*)carve(983040);     // [1920][128]
  float* WcT = (float*)carve(491520);     // [1920][64]
  float* WxG = (float*)carve(6291456);    // [2048][6][128]
  float* WxC = (float*)carve(3145728);    // [2048][6][64]
  float* bgv = (float*)carve(1048576);    // [2048][128]
  float* bcv = (float*)carve(524288);     // [2048][64]
  // per-half scratch (NB = 8 batches)
  float* Ht  = (float*)carve(4194304);    // h feature-major [512][2048]
  float* Y1t = (float*)carve(4194304);    // [512][2048]
  float* Y2t = (float*)carve(4194304);
  float* RHt = (float*)carve(4194304);    // r*h feature-major
  float* Hs  = (float*)carve(4194304);    // h node-major [16384][64]
  float* ubuf= (float*)carve(4194304);    // u gate [16384][64]
  float* X0t = ubuf;                      // alias: X0t consumed before ubuf written

  prep_AT_k<<<16384, 256, 0, stream>>>(A, AT);
  prep_wt_k<128><<<960, 256, 0, stream>>>(Wgp, WgT);
  prep_wt_k<64><<<480, 256, 0, stream>>>(Wcp, WcT);
  prep_wx_k<128><<<6144, 256, 0, stream>>>(E, Wgp, WxG);
  prep_wx_k<64><<<3072, 256, 0, stream>>>(E, Wcp, WxC);
  prep_b_k<128><<<1024, 256, 0, stream>>>(E, bgp, bgv);
  prep_b_k<64><<<512, 256, 0, stream>>>(E, bcp, bcv);
  prep_x0_k<<<3072, 256, 0, stream>>>(x, X0t);
  spmm_k<<<dim3(16, 12), 128, 0, stream>>>(X0t, AT, X1t);
  spmm_k<<<dim3(16, 12), 128, 0, stream>>>(X1t, AT, X2t);

  for (int half = 0; half < 2; ++half) {
    const int b0 = half * 8;
    hipMemsetAsync(Hs, 0, 4194304, stream);
    hipMemsetAsync(Ht, 0, 4194304, stream);
    for (int lt = 0; lt < 12; ++lt) {
      spmm_k<<<dim3(16, 16), 128, 0, stream>>>(Ht, AT, Y1t);
      spmm_k<<<dim3(16, 16), 128, 0, stream>>>(Y1t, AT, Y2t);
      gate_k<<<1024, 128, 0, stream>>>(Y1t, Y2t, Hs, WgT, E, bgv, WxG, x,
                                       X1t, X2t, RHt, ubuf, lt, b0);
      spmm_k<<<dim3(16, 16), 128, 0, stream>>>(RHt, AT, Y1t);
      spmm_k<<<dim3(16, 16), 128, 0, stream>>>(Y1t, AT, Y2t);
      cand_k<<<1024, 128, 0, stream>>>(Y1t, Y2t, RHt, WcT, E, bcv, WxC, x,
                                       X1t, X2t, ubuf, Hs, Ht, out, lt, b0);
    }
    hipMemcpyAsync(out + 25165824 + half * 1048576, Hs, 4194304,
                   hipMemcpyDeviceToDevice, stream);
  }
}

// Round 7
// 10835.504 us; speedup vs baseline: 5.9679x; 5.9679x over previous
//
#include <hip/hip_runtime.h>
#include <cstdint>
#include <cstddef>

typedef _Float16 h16;
typedef h16 v8h __attribute__((ext_vector_type(8)));
typedef float v4f __attribute__((ext_vector_type(4)));

constexpr int NN = 2048;
constexpr float INV_N = 1.0f / 2048.0f;
constexpr int LP = 72;  // LDS row stride in halves (64 + 8 pad)

// ---------------- diagnostic fill ----------------
__global__ void fill_k(float* __restrict__ o, float v, size_t ntot) {
  size_t i = (size_t)blockIdx.x * 256 + threadIdx.x;
  if (i < ntot) o[i] = v;
}

// ---------------- prep kernels ----------------

// split A*2048 into hi/lo fp16
__global__ void prep_Asplit_k(const float* __restrict__ A,
                              h16* __restrict__ hi, h16* __restrict__ lo) {
  int tid = blockIdx.x * 256 + threadIdx.x;   // 4M
  float v = A[tid] * 2048.0f;
  h16 h = (h16)v;
  hi[tid] = h;
  lo[tid] = (h16)(v - (float)h);
}

// X0[c=(lt*16+b)*2+ii][n] = x[b][lt][n][ii], split hi/lo
__global__ void prep_x0split_k(const float* __restrict__ x,
                               h16* __restrict__ hi, h16* __restrict__ lo) {
  int tid = blockIdx.x * 256 + threadIdx.x;   // 384*2048
  int n = tid & 2047, c = tid >> 11;
  int ii = c & 1, b = (c >> 1) & 15, lt = c >> 5;
  float v = x[(((size_t)(b * 12 + lt)) * NN + n) * 2 + ii];
  h16 h = (h16)v;
  hi[tid] = h;
  lo[tid] = (h16)(v - (float)h);
}

// Folded pool weights, k-major: WT[(d*192+rem)*CO+o]
// rem<64 (h/rh term): P[d][0]-P[d][2]; [64,128) (A@v): P[d][1]; [128,192) (A2@v): 2*P[d][2]
template<int CO>
__global__ void prep_wt_k(const float* __restrict__ Wp, float* __restrict__ WT) {
  int tid = blockIdx.x * 256 + threadIdx.x;   // 1920*CO
  int o = tid & (CO - 1), j = tid / CO;
  int d = j / 192, rem = j - d * 192;
  int k = rem >> 6, i = rem & 63;
  float v;
  if (k == 0)
    v = Wp[((size_t)((d * 3 + 0) * 66 + i)) * CO + o] -
        Wp[((size_t)((d * 3 + 2) * 66 + i)) * CO + o];
  else if (k == 1)
    v = Wp[((size_t)((d * 3 + 1) * 66 + i)) * CO + o];
  else
    v = 2.f * Wp[((size_t)((d * 3 + 2) * 66 + i)) * CO + o];
  WT[tid] = v;
}

// Folded x-col weights: Wx[n][t6=k*2+ii][o], applied to (x0, A@x, A2@x)
template<int CO>
__global__ void prep_wx_k(const float* __restrict__ E, const float* __restrict__ Wp,
                          float* __restrict__ Wx) {
  int tid = blockIdx.x * 256 + threadIdx.x;   // 2048*6*CO
  int o = tid & (CO - 1), t6 = (tid / CO) % 6, n = tid / (6 * CO);
  int k = t6 >> 1, ii = t6 & 1;
  float s = 0.f;
  for (int d = 0; d < 10; ++d) {
    float p0 = Wp[((size_t)((d * 3 + 0) * 66 + 64 + ii)) * CO + o];
    float p1 = Wp[((size_t)((d * 3 + 1) * 66 + 64 + ii)) * CO + o];
    float p2 = Wp[((size_t)((d * 3 + 2) * 66 + 64 + ii)) * CO + o];
    float v = (k == 0) ? (p0 - p2) : (k == 1 ? p1 : 2.f * p2);
    s += E[n * 10 + d] * v;
  }
  Wx[tid] = s;
}

template<int CO>
__global__ void prep_b_k(const float* __restrict__ E, const float* __restrict__ bp,
                         float* __restrict__ bv) {
  int tid = blockIdx.x * 256 + threadIdx.x;   // 2048*CO
  int o = tid & (CO - 1), n = tid / CO;
  float s = 0.f;
  for (int d = 0; d < 10; ++d) s += E[n * 10 + d] * bp[d * CO + o];
  bv[tid] = s;
}

// ---------------- split-fp16 MFMA SpMM ----------------
// out[c][n] = INV_N * sum_m (Ih+Il)[c][m] * (Bh+Bl)[n][m]   (3-MFMA Markidis split)
// BM=64, BN=64, BK=64; 512 threads, 8 waves 2x4, wave tile 32x16.
// OM bit0: write fp32 oF[c][n]; OM bit1: write split oH/oL[c][n].
template<int OM>
__global__ __launch_bounds__(512) void sgemm_k(
    const h16* __restrict__ Ih, const h16* __restrict__ Il,
    const h16* __restrict__ Bh, const h16* __restrict__ Bl,
    float* __restrict__ oF, h16* __restrict__ oH, h16* __restrict__ oL) {
  const int m0 = blockIdx.x * 64, n0 = blockIdx.y * 64;
  __shared__ __align__(16) h16 sAh[64 * LP], sAl[64 * LP];
  __shared__ __align__(16) h16 sBh[64 * LP], sBl[64 * LP];
  const int tid = threadIdx.x, lane = tid & 63, w = tid >> 6;
  const int wr = w >> 2, wc = w & 3;
  v4f acc[2] = {};
  const int sr = tid >> 3, sc = (tid & 7) * 8;
  v8h rah = *(const v8h*)(Ih + (size_t)(m0 + sr) * NN + sc);
  v8h ral = *(const v8h*)(Il + (size_t)(m0 + sr) * NN + sc);
  v8h rbh = *(const v8h*)(Bh + (size_t)(n0 + sr) * NN + sc);
  v8h rbl = *(const v8h*)(Bl + (size_t)(n0 + sr) * NN + sc);
  for (int kt = 0; kt < NN; kt += 64) {
    __syncthreads();
    *(v8h*)(sAh + sr * LP + sc) = rah;
    *(v8h*)(sAl + sr * LP + sc) = ral;
    *(v8h*)(sBh + sr * LP + sc) = rbh;
    *(v8h*)(sBl + sr * LP + sc) = rbl;
    __syncthreads();
    if (kt + 64 < NN) {
      const int k2 = kt + 64 + sc;
      rah = *(const v8h*)(Ih + (size_t)(m0 + sr) * NN + k2);
      ral = *(const v8h*)(Il + (size_t)(m0 + sr) * NN + k2);
      rbh = *(const v8h*)(Bh + (size_t)(n0 + sr) * NN + k2);
      rbl = *(const v8h*)(Bl + (size_t)(n0 + sr) * NN + k2);
    }
#pragma unroll
    for (int kk = 0; kk < 2; ++kk) {
      const int ko = kk * 32 + (lane >> 4) * 8;
      const int rs = lane & 15;
      v8h a0h = *(const v8h*)(sAh + (wr * 32 + rs) * LP + ko);
      v8h a1h = *(const v8h*)(sAh + (wr * 32 + 16 + rs) * LP + ko);
      v8h a0l = *(const v8h*)(sAl + (wr * 32 + rs) * LP + ko);
      v8h a1l = *(const v8h*)(sAl + (wr * 32 + 16 + rs) * LP + ko);
      v8h b0h = *(const v8h*)(sBh + (wc * 16 + rs) * LP + ko);
      v8h b0l = *(const v8h*)(sBl + (wc * 16 + rs) * LP + ko);
      acc[0] = __builtin_amdgcn_mfma_f32_16x16x32_f16(a0h, b0h, acc[0], 0, 0, 0);
      acc[1] = __builtin_amdgcn_mfma_f32_16x16x32_f16(a1h, b0h, acc[1], 0, 0, 0);
      acc[0] = __builtin_amdgcn_mfma_f32_16x16x32_f16(a0l, b0h, acc[0], 0, 0, 0);
      acc[1] = __builtin_amdgcn_mfma_f32_16x16x32_f16(a1l, b0h, acc[1], 0, 0, 0);
      acc[0] = __builtin_amdgcn_mfma_f32_16x16x32_f16(a0h, b0l, acc[0], 0, 0, 0);
      acc[1] = __builtin_amdgcn_mfma_f32_16x16x32_f16(a1h, b0l, acc[1], 0, 0, 0);
    }
  }
  const int l15 = lane & 15, l4 = (lane >> 4) * 4;
  const int n = n0 + wc * 16 + l15;
#pragma unroll
  for (int mi = 0; mi < 2; ++mi) {
#pragma unroll
    for (int r = 0; r < 4; ++r) {
      const int c = m0 + wr * 32 + mi * 16 + l4 + r;
      const float v = acc[mi][r] * INV_N;
      if constexpr (OM & 1) oF[(size_t)c * NN + n] = v;
      if constexpr (OM & 2) {
        h16 h = (h16)v;
        oH[(size_t)c * NN + n] = h;
        oL[(size_t)c * NN + n] = (h16)(v - (float)h);
      }
    }
  }
}

// ---------------- gate: stage {h, y1, y2}, pool-factored fp32 GEMM, epilogue ----------------
__global__ __launch_bounds__(128) void gate_k(
    const h16* __restrict__ y1h, const h16* __restrict__ y1l,
    const float* __restrict__ y2g, const float* __restrict__ Hs,
    const float* __restrict__ WT, const float* __restrict__ E,
    const float* __restrict__ bgv, const float* __restrict__ Wx,
    const float* __restrict__ x, const float* __restrict__ X1t,
    const float* __restrict__ X2t, h16* __restrict__ RHh,
    h16* __restrict__ RHl, float* __restrict__ ubuf, int lt, int b0) {
  const int R0 = blockIdx.x * 16;
  const int bl = R0 >> 11, n0 = R0 & 2047;
  __shared__ float xs[16][200];
  const int tid = threadIdx.x;
  {  // k0: h (row-contiguous from Hs)
    const int rr = tid >> 3, q = tid & 7;
    const float* hp = Hs + (size_t)(R0 + rr) * 64 + q * 8;
#pragma unroll
    for (int i = 0; i < 8; ++i) xs[rr][q * 8 + i] = hp[i];
  }
  {  // k1 (y1 hi+lo), k2 (y2 fp32) — n-coalesced gathers
    const int nc = tid & 15, jl = tid >> 4;
#pragma unroll
    for (int jj = 0; jj < 8; ++jj) {
      const int j = jl * 8 + jj;
      const size_t fo = (size_t)(bl * 64 + j) * NN + n0 + nc;
      xs[nc][64 + j] = (float)y1h[fo] + (float)y1l[fo];
      xs[nc][128 + j] = y2g[fo];
    }
  }
  __syncthreads();
  const int o = tid;
  float acc[16];
#pragma unroll
  for (int rr = 0; rr < 16; ++rr) acc[rr] = 0.f;
  for (int d = 0; d < 10; ++d) {
    float tmp[16];
#pragma unroll
    for (int rr = 0; rr < 16; ++rr) tmp[rr] = 0.f;
    for (int j = 0; j < 192; ++j) {
      const float ww = WT[(size_t)(d * 192 + j) * 128 + o];
#pragma unroll
      for (int rr = 0; rr < 16; ++rr) tmp[rr] += xs[rr][j] * ww;
    }
#pragma unroll
    for (int rr = 0; rr < 16; ++rr)
      acc[rr] += E[(n0 + rr) * 10 + d] * tmp[rr];
  }
  const int gb = b0 + bl;
  const size_t xbase = ((size_t)(gb * 12 + lt)) * NN;
  const size_t c1 = ((size_t)(lt * 16 + gb)) * 2;
  for (int rr = 0; rr < 16; ++rr) {
    const int n = n0 + rr;
    const size_t R = (size_t)R0 + rr;
    const float x0a = x[(xbase + n) * 2 + 0];
    const float x0b = x[(xbase + n) * 2 + 1];
    const float x1a = X1t[c1 * NN + n];
    const float x1b = X1t[(c1 + 1) * NN + n];
    const float x2a = X2t[c1 * NN + n];
    const float x2b = X2t[(c1 + 1) * NN + n];
    const float* wx = Wx + (size_t)n * 768;
    float pre = acc[rr] + bgv[(size_t)n * 128 + o]
              + x0a * wx[o]       + x0b * wx[128 + o]
              + x1a * wx[256 + o] + x1b * wx[384 + o]
              + x2a * wx[512 + o] + x2b * wx[640 + o];
    const float g = 1.f / (1.f + expf(-pre));
    if (o < 64) {
      const float rh = g * Hs[R * 64 + o];
      const size_t fo = (size_t)(bl * 64 + o) * NN + n;
      h16 h = (h16)rh;
      RHh[fo] = h;
      RHl[fo] = (h16)(rh - (float)h);
    } else {
      ubuf[R * 64 + (o - 64)] = g;
    }
  }
}

// ---------------- cand: stage {rh, y1c, y2c}, GEMM, GRU update ----------------
__global__ __launch_bounds__(128) void cand_k(
    const h16* __restrict__ y1h, const h16* __restrict__ y1l,
    const float* __restrict__ y2c, const h16* __restrict__ RHh,
    const h16* __restrict__ RHl, const float* __restrict__ WT,
    const float* __restrict__ E, const float* __restrict__ bcv,
    const float* __restrict__ Wx, const float* __restrict__ x,
    const float* __restrict__ X1t, const float* __restrict__ X2t,
    const float* __restrict__ ubuf, float* __restrict__ Hs,
    h16* __restrict__ Hh, h16* __restrict__ Hl,
    float* __restrict__ out, int lt, int b0) {
  const int R0 = blockIdx.x * 16;
  const int bl = R0 >> 11, n0 = R0 & 2047;
  __shared__ float xs[16][200];
  const int tid = threadIdx.x;
  {
    const int nc = tid & 15, jl = tid >> 4;
#pragma unroll
    for (int jj = 0; jj < 8; ++jj) {
      const int j = jl * 8 + jj;
      const size_t fo = (size_t)(bl * 64 + j) * NN + n0 + nc;
      xs[nc][j] = (float)RHh[fo] + (float)RHl[fo];
      xs[nc][64 + j] = (float)y1h[fo] + (float)y1l[fo];
      xs[nc][128 + j] = y2c[fo];
    }
  }
  __syncthreads();
  const int o = tid & 63, hh = tid >> 6;
  float acc[8];
#pragma unroll
  for (int r8 = 0; r8 < 8; ++r8) acc[r8] = 0.f;
  for (int d = 0; d < 10; ++d) {
    float tmp[8];
#pragma unroll
    for (int r8 = 0; r8 < 8; ++r8) tmp[r8] = 0.f;
    for (int j = 0; j < 192; ++j) {
      const float ww = WT[(size_t)(d * 192 + j) * 64 + o];
#pragma unroll
      for (int r8 = 0; r8 < 8; ++r8) tmp[r8] += xs[hh * 8 + r8][j] * ww;
    }
#pragma unroll
    for (int r8 = 0; r8 < 8; ++r8)
      acc[r8] += E[(n0 + hh * 8 + r8) * 10 + d] * tmp[r8];
  }
  const int gb = b0 + bl;
  const size_t xbase = ((size_t)(gb * 12 + lt)) * NN;
  const size_t c1 = ((size_t)(lt * 16 + gb)) * 2;
  for (int r8 = 0; r8 < 8; ++r8) {
    const int rr = hh * 8 + r8;
    const int n = n0 + rr;
    const size_t R = (size_t)R0 + rr;
    const float x0a = x[(xbase + n) * 2 + 0];
    const float x0b = x[(xbase + n) * 2 + 1];
    const float x1a = X1t[c1 * NN + n];
    const float x1b = X1t[(c1 + 1) * NN + n];
    const float x2a = X2t[c1 * NN + n];
    const float x2b = X2t[(c1 + 1) * NN + n];
    const float* wx = Wx + (size_t)n * 384;
    float pre = acc[r8] + bcv[(size_t)n * 64 + o]
              + x0a * wx[o]       + x0b * wx[64 + o]
              + x1a * wx[128 + o] + x1b * wx[192 + o]
              + x2a * wx[256 + o] + x2b * wx[320 + o];
    const float cv = tanhf(pre);
    const float u = ubuf[R * 64 + o];
    const float hold = Hs[R * 64 + o];
    const float hn = u * hold + (1.f - u) * cv;
    Hs[R * 64 + o] = hn;
    out[(xbase + n) * 64 + o] = hn;
    const size_t fo = (size_t)(bl * 64 + o) * NN + n;
    h16 h = (h16)hn;
    Hh[fo] = h;
    Hl[fo] = (h16)(hn - (float)h);
  }
}

// ---------------- launch ----------------
extern "C" void kernel_launch(void* const* d_in, const int* in_sizes, int n_in,
                              void* d_out, int out_size, void* d_ws, size_t ws_size,
                              hipStream_t stream) {
  float* out = (float*)d_out;

  const bool in_ok = (n_in == 7) &&
      in_sizes[0] == 786432 && in_sizes[1] == 20480 && in_sizes[2] == 4194304 &&
      in_sizes[3] == 253440 && in_sizes[4] == 1280 &&
      in_sizes[5] == 126720 && in_sizes[6] == 640 && out_size == 27262976;
  if (!in_ok) {
    fill_k<<<(out_size + 255) / 256, 256, 0, stream>>>(out, 77.0f, (size_t)out_size);
    return;
  }
  constexpr size_t NEED = 60719104;
  if (ws_size < NEED) {
    fill_k<<<106496, 256, 0, stream>>>(out, 42.0f, 27262976);
    return;
  }

  const float* x   = (const float*)d_in[0];
  const float* E   = (const float*)d_in[1];
  const float* A   = (const float*)d_in[2];
  const float* Wgp = (const float*)d_in[3];
  const float* bgp = (const float*)d_in[4];
  const float* Wcp = (const float*)d_in[5];
  const float* bcp = (const float*)d_in[6];

  char* p = (char*)d_ws;
  auto carve = [&](size_t bytes) { char* r = p; p += bytes; return r; };
  // shared (35,553,280 B)
  h16*   Ah  = (h16*)carve(8388608);    // fp16 hi of A*2048 [2048][2048]
  h16*   Al  = (h16*)carve(8388608);    // fp16 lo
  float* X1t = (float*)carve(3145728);  // A@x   [384][2048] fp32
  float* X2t = (float*)carve(3145728);  // A@(A@x)
  float* WgT = (float*)carve(983040);   // folded [1920][128]
  float* WcT = (float*)carve(491520);   // folded [1920][64]
  float* WxG = (float*)carve(6291456);  // folded [2048][6][128]
  float* WxC = (float*)carve(3145728);  // folded [2048][6][64]
  float* bgv = (float*)carve(1048576);
  float* bcv = (float*)carve(524288);
  // per-half (25,165,824 B)
  h16*   Hh  = (h16*)carve(2097152);    // h split hi, feature-major [512][2048]
  h16*   Hl  = (h16*)carve(2097152);
  h16*   RHh = (h16*)carve(2097152);    // r*h split
  h16*   RHl = (h16*)carve(2097152);
  h16*   y1h = (h16*)carve(2097152);    // y1 split
  h16*   y1l = (h16*)carve(2097152);
  float* y2  = (float*)carve(4194304);  // y2 fp32 feature-major [512][2048]
  float* Hs  = (float*)carve(4194304);  // h fp32 node-major [16384][64] (primary state)
  float* ubuf= (float*)carve(4194304);  // u fp32 [16384][64]
  // pre-loop aliases (dead before half loop)
  h16* X0h = Hh;   h16* X0l = Hl;       // [384][2048] each (1.5 MB < 2 MB)
  h16* X1h = RHh;  h16* X1l = RHl;

  prep_Asplit_k<<<16384, 256, 0, stream>>>(A, Ah, Al);
  prep_wt_k<128><<<960, 256, 0, stream>>>(Wgp, WgT);
  prep_wt_k<64><<<480, 256, 0, stream>>>(Wcp, WcT);
  prep_wx_k<128><<<6144, 256, 0, stream>>>(E, Wgp, WxG);
  prep_wx_k<64><<<3072, 256, 0, stream>>>(E, Wcp, WxC);
  prep_b_k<128><<<1024, 256, 0, stream>>>(E, bgp, bgv);
  prep_b_k<64><<<512, 256, 0, stream>>>(E, bcp, bcv);
  // x-path: X1 = A@x (fp32 + split), X2 = A@X1 (fp32)
  prep_x0split_k<<<3072, 256, 0, stream>>>(x, X0h, X0l);
  sgemm_k<3><<<dim3(6, 32), 512, 0, stream>>>(X0h, X0l, Ah, Al, X1t, X1h, X1l);
  sgemm_k<1><<<dim3(6, 32), 512, 0, stream>>>(X1h, X1l, Ah, Al, X2t, nullptr, nullptr);

  for (int half = 0; half < 2; ++half) {
    const int b0 = half * 8;
    hipMemsetAsync(Hs, 0, 4194304, stream);
    hipMemsetAsync(Hh, 0, 2097152, stream);
    hipMemsetAsync(Hl, 0, 2097152, stream);
    for (int lt = 0; lt < 12; ++lt) {
      sgemm_k<2><<<dim3(8, 32), 512, 0, stream>>>(Hh, Hl, Ah, Al, nullptr, y1h, y1l);
      sgemm_k<1><<<dim3(8, 32), 512, 0, stream>>>(y1h, y1l, Ah, Al, y2, nullptr, nullptr);
      gate_k<<<1024, 128, 0, stream>>>(y1h, y1l, y2, Hs, WgT, E, bgv, WxG, x,
                                       X1t, X2t, RHh, RHl, ubuf, lt, b0);
      sgemm_k<2><<<dim3(8, 32), 512, 0, stream>>>(RHh, RHl, Ah, Al, nullptr, y1h, y1l);
      sgemm_k<1><<<dim3(8, 32), 512, 0, stream>>>(y1h, y1l, Ah, Al, y2, nullptr, nullptr);
      cand_k<<<1024, 128, 0, stream>>>(y1h, y1l, y2, RHh, RHl, WcT, E, bcv, WxC, x,
                                       X1t, X2t, ubuf, Hs, Hh, Hl, out, lt, b0);
    }
    hipMemcpyAsync(out + 25165824 + half * 1048576, Hs, 4194304,
                   hipMemcpyDeviceToDevice, stream);
  }
}

// Round 8
// 5297.882 us; speedup vs baseline: 12.2059x; 2.0453x over previous
//
#include <hip/hip_runtime.h>
#include <cstdint>
#include <cstddef>

typedef _Float16 h16;
typedef h16 v8h __attribute__((ext_vector_type(8)));
typedef h16 v4h __attribute__((ext_vector_type(4)));
typedef float v4f __attribute__((ext_vector_type(4)));

constexpr int NN = 2048;
constexpr float INV_N = 1.0f / 2048.0f;
constexpr int LP = 72;  // LDS row stride in halves (64 + 8 pad)

#define MFMA16(a, b, c) __builtin_amdgcn_mfma_f32_16x16x32_f16((a), (b), (c), 0, 0, 0)

// ---------------- diagnostic fill ----------------
__global__ void fill_k(float* __restrict__ o, float v, size_t ntot) {
  size_t i = (size_t)blockIdx.x * 256 + threadIdx.x;
  if (i < ntot) o[i] = v;
}

// ---------------- prep kernels ----------------

__global__ void prep_Asplit_k(const float* __restrict__ A,
                              h16* __restrict__ hi, h16* __restrict__ lo) {
  int tid = blockIdx.x * 256 + threadIdx.x;   // 4M
  float v = A[tid] * 2048.0f;
  h16 h = (h16)v;
  hi[tid] = h;
  lo[tid] = (h16)(v - (float)h);
}

__global__ void prep_x0split_k(const float* __restrict__ x,
                               h16* __restrict__ hi, h16* __restrict__ lo) {
  int tid = blockIdx.x * 256 + threadIdx.x;   // 384*2048
  int n = tid & 2047, c = tid >> 11;
  int ii = c & 1, b = (c >> 1) & 15, lt = c >> 5;
  float v = x[(((size_t)(b * 12 + lt)) * NN + n) * 2 + ii];
  h16 h = (h16)v;
  hi[tid] = h;
  lo[tid] = (h16)(v - (float)h);
}

// transposed + split folded pool weights: WT[o][k = d*192 + jb*64 + j]
// jb0 (h/rh): P0-P2; jb1 (A@v): P1; jb2 (A2@v): 2*P2
template<int CO>
__global__ void prep_wts_k(const float* __restrict__ Wp,
                           h16* __restrict__ WTh, h16* __restrict__ WTl) {
  int tid = blockIdx.x * 256 + threadIdx.x;   // CO*1920
  int kk = tid % 1920, o = tid / 1920;
  int d = kk / 192, rem = kk - d * 192;
  int jb = rem >> 6, i = rem & 63;
  float v;
  if (jb == 0)
    v = Wp[((size_t)((d * 3 + 0) * 66 + i)) * CO + o] -
        Wp[((size_t)((d * 3 + 2) * 66 + i)) * CO + o];
  else if (jb == 1)
    v = Wp[((size_t)((d * 3 + 1) * 66 + i)) * CO + o];
  else
    v = 2.f * Wp[((size_t)((d * 3 + 2) * 66 + i)) * CO + o];
  h16 h = (h16)v;
  WTh[tid] = h;
  WTl[tid] = (h16)(v - (float)h);
}

// Folded x-col weights (fp32): Wx[n][t6=k*2+ii][o] for (x0, A@x, A2@x)
template<int CO>
__global__ void prep_wx_k(const float* __restrict__ E, const float* __restrict__ Wp,
                          float* __restrict__ Wx) {
  int tid = blockIdx.x * 256 + threadIdx.x;   // 2048*6*CO
  int o = tid & (CO - 1), t6 = (tid / CO) % 6, n = tid / (6 * CO);
  int k = t6 >> 1, ii = t6 & 1;
  float s = 0.f;
  for (int d = 0; d < 10; ++d) {
    float p0 = Wp[((size_t)((d * 3 + 0) * 66 + 64 + ii)) * CO + o];
    float p1 = Wp[((size_t)((d * 3 + 1) * 66 + 64 + ii)) * CO + o];
    float p2 = Wp[((size_t)((d * 3 + 2) * 66 + 64 + ii)) * CO + o];
    float v = (k == 0) ? (p0 - p2) : (k == 1 ? p1 : 2.f * p2);
    s += E[n * 10 + d] * v;
  }
  Wx[tid] = s;
}

template<int CO>
__global__ void prep_b_k(const float* __restrict__ E, const float* __restrict__ bp,
                         float* __restrict__ bv) {
  int tid = blockIdx.x * 256 + threadIdx.x;   // 2048*CO
  int o = tid & (CO - 1), n = tid / CO;
  float s = 0.f;
  for (int d = 0; d < 10; ++d) s += E[n * 10 + d] * bp[d * CO + o];
  bv[tid] = s;
}

// ---------------- split-fp16 MFMA SpMM (r7-proven body) ----------------
// out[c][n] = INV_N * sum_m (Ih+Il)[c][m] * (Bh+Bl)[n][m]
// OM bit0: oF fp32 feature; bit1: oH/oL split feature; bit2: xs scatter @xoff.
template<int OM>
__global__ __launch_bounds__(512) void sgemm_k(
    const h16* __restrict__ Ih, const h16* __restrict__ Il,
    const h16* __restrict__ Bh, const h16* __restrict__ Bl,
    float* __restrict__ oF, h16* __restrict__ oH, h16* __restrict__ oL,
    float* __restrict__ xsv, int xoff) {
  const int m0 = blockIdx.x * 64, n0 = blockIdx.y * 64;
  __shared__ __align__(16) h16 sAh[64 * LP], sAl[64 * LP];
  __shared__ __align__(16) h16 sBh[64 * LP], sBl[64 * LP];
  const int tid = threadIdx.x, lane = tid & 63, w = tid >> 6;
  const int wr = w >> 2, wc = w & 3;
  v4f acc[2] = {};
  const int sr = tid >> 3, sc = (tid & 7) * 8;
  v8h rah = *(const v8h*)(Ih + (size_t)(m0 + sr) * NN + sc);
  v8h ral = *(const v8h*)(Il + (size_t)(m0 + sr) * NN + sc);
  v8h rbh = *(const v8h*)(Bh + (size_t)(n0 + sr) * NN + sc);
  v8h rbl = *(const v8h*)(Bl + (size_t)(n0 + sr) * NN + sc);
  for (int kt = 0; kt < NN; kt += 64) {
    __syncthreads();
    *(v8h*)(sAh + sr * LP + sc) = rah;
    *(v8h*)(sAl + sr * LP + sc) = ral;
    *(v8h*)(sBh + sr * LP + sc) = rbh;
    *(v8h*)(sBl + sr * LP + sc) = rbl;
    __syncthreads();
    if (kt + 64 < NN) {
      const int k2 = kt + 64 + sc;
      rah = *(const v8h*)(Ih + (size_t)(m0 + sr) * NN + k2);
      ral = *(const v8h*)(Il + (size_t)(m0 + sr) * NN + k2);
      rbh = *(const v8h*)(Bh + (size_t)(n0 + sr) * NN + k2);
      rbl = *(const v8h*)(Bl + (size_t)(n0 + sr) * NN + k2);
    }
#pragma unroll
    for (int kk = 0; kk < 2; ++kk) {
      const int ko = kk * 32 + (lane >> 4) * 8;
      const int rs = lane & 15;
      v8h a0h = *(const v8h*)(sAh + (wr * 32 + rs) * LP + ko);
      v8h a1h = *(const v8h*)(sAh + (wr * 32 + 16 + rs) * LP + ko);
      v8h a0l = *(const v8h*)(sAl + (wr * 32 + rs) * LP + ko);
      v8h a1l = *(const v8h*)(sAl + (wr * 32 + 16 + rs) * LP + ko);
      v8h b0h = *(const v8h*)(sBh + (wc * 16 + rs) * LP + ko);
      v8h b0l = *(const v8h*)(sBl + (wc * 16 + rs) * LP + ko);
      acc[0] = MFMA16(a0h, b0h, acc[0]);
      acc[1] = MFMA16(a1h, b0h, acc[1]);
      acc[0] = MFMA16(a0l, b0h, acc[0]);
      acc[1] = MFMA16(a1l, b0h, acc[1]);
      acc[0] = MFMA16(a0h, b0l, acc[0]);
      acc[1] = MFMA16(a1h, b0l, acc[1]);
    }
  }
  const int l15 = lane & 15, l4 = (lane >> 4) * 4;
  const int n = n0 + wc * 16 + l15;
#pragma unroll
  for (int mi = 0; mi < 2; ++mi) {
    const int cb = m0 + wr * 32 + mi * 16 + l4;
    float vv[4];
#pragma unroll
    for (int r = 0; r < 4; ++r) {
      vv[r] = acc[mi][r] * INV_N;
      if constexpr (OM & 1) oF[(size_t)(cb + r) * NN + n] = vv[r];
      if constexpr (OM & 2) {
        h16 h = (h16)vv[r];
        oH[(size_t)(cb + r) * NN + n] = h;
        oL[(size_t)(cb + r) * NN + n] = (h16)(vv[r] - (float)h);
      }
    }
    if constexpr (OM & 4) {
      v4f pv = {vv[0], vv[1], vv[2], vv[3]};
      *(v4f*)(xsv + ((size_t)(cb >> 6) * 2048 + n) * 192 + xoff + (cb & 63)) = pv;
    }
  }
}

// ---------------- MFMA gate: pre = xs~ (E-scaled, split) @ WgT(split) + epilogue ----------------
// BM=64 R-rows, BN=128 o; 512 thr, 8 waves 2x4, wave 32x32; 30 K-tiles (d,jb).
__global__ __launch_bounds__(512) void mgate_k(
    const float* __restrict__ xs, const h16* __restrict__ Bh, const h16* __restrict__ Bl,
    const float* __restrict__ E, const float* __restrict__ bgv,
    const float* __restrict__ Wx, const float* __restrict__ x,
    const float* __restrict__ X1t, const float* __restrict__ X2t,
    float* __restrict__ RHs, float* __restrict__ ubuf,
    h16* __restrict__ HRh, h16* __restrict__ HRl, int lt, int b0) {
  const int R0 = blockIdx.x * 64;
  const int bl = R0 >> 11, n0 = R0 & 2047;
  __shared__ __align__(16) h16 sAh[64 * LP], sAl[64 * LP];
  __shared__ __align__(16) h16 sBh[128 * LP], sBl[128 * LP];
  const int tid = threadIdx.x, lane = tid & 63, w = tid >> 6;
  const int wr = w >> 2, wc = w & 3;
  v4f acc[2][2] = {};
  const int asr = tid >> 3, asc = (tid & 7) * 8;   // A: 64 rows x 8 f32
  const int bsr = tid >> 2, bsc = (tid & 3) * 16;  // B: 128 rows x 16 h16
  const float* arow = xs + (size_t)(R0 + asr) * 192 + asc;
  const float* erow = E + (size_t)(n0 + asr) * 10;
  const h16* bhrow = Bh + (size_t)bsr * 1920 + bsc;
  const h16* blrow = Bl + (size_t)bsr * 1920 + bsc;
  int d = 0, jb = 0;
  for (int t = 0; t < 30; ++t) {
    const float e = erow[d];
    v4f a0 = *(const v4f*)(arow + jb * 64);
    v4f a1 = *(const v4f*)(arow + jb * 64 + 4);
    v8h ah, al;
#pragma unroll
    for (int q = 0; q < 4; ++q) {
      float v = a0[q] * e; h16 hh = (h16)v; ah[q] = hh; al[q] = (h16)(v - (float)hh);
      v = a1[q] * e; hh = (h16)v; ah[4 + q] = hh; al[4 + q] = (h16)(v - (float)hh);
    }
    v8h wh0 = *(const v8h*)(bhrow + t * 64);
    v8h wh1 = *(const v8h*)(bhrow + t * 64 + 8);
    v8h wl0 = *(const v8h*)(blrow + t * 64);
    v8h wl1 = *(const v8h*)(blrow + t * 64 + 8);
    __syncthreads();
    *(v8h*)(sAh + asr * LP + asc) = ah;
    *(v8h*)(sAl + asr * LP + asc) = al;
    *(v8h*)(sBh + bsr * LP + bsc) = wh0;
    *(v8h*)(sBh + bsr * LP + bsc + 8) = wh1;
    *(v8h*)(sBl + bsr * LP + bsc) = wl0;
    *(v8h*)(sBl + bsr * LP + bsc + 8) = wl1;
    __syncthreads();
#pragma unroll
    for (int kk = 0; kk < 2; ++kk) {
      const int ko = kk * 32 + (lane >> 4) * 8;
      const int rs = lane & 15;
      v8h Ah0 = *(const v8h*)(sAh + (wr * 32 + rs) * LP + ko);
      v8h Ah1 = *(const v8h*)(sAh + (wr * 32 + 16 + rs) * LP + ko);
      v8h Al0 = *(const v8h*)(sAl + (wr * 32 + rs) * LP + ko);
      v8h Al1 = *(const v8h*)(sAl + (wr * 32 + 16 + rs) * LP + ko);
      v8h Bh0 = *(const v8h*)(sBh + (wc * 32 + rs) * LP + ko);
      v8h Bh1 = *(const v8h*)(sBh + (wc * 32 + 16 + rs) * LP + ko);
      v8h Bl0 = *(const v8h*)(sBl + (wc * 32 + rs) * LP + ko);
      v8h Bl1 = *(const v8h*)(sBl + (wc * 32 + 16 + rs) * LP + ko);
      acc[0][0] = MFMA16(Ah0, Bh0, acc[0][0]);
      acc[0][1] = MFMA16(Ah0, Bh1, acc[0][1]);
      acc[1][0] = MFMA16(Ah1, Bh0, acc[1][0]);
      acc[1][1] = MFMA16(Ah1, Bh1, acc[1][1]);
      acc[0][0] = MFMA16(Al0, Bh0, acc[0][0]);
      acc[0][1] = MFMA16(Al0, Bh1, acc[0][1]);
      acc[1][0] = MFMA16(Al1, Bh0, acc[1][0]);
      acc[1][1] = MFMA16(Al1, Bh1, acc[1][1]);
      acc[0][0] = MFMA16(Ah0, Bl0, acc[0][0]);
      acc[0][1] = MFMA16(Ah0, Bl1, acc[0][1]);
      acc[1][0] = MFMA16(Ah1, Bl0, acc[1][0]);
      acc[1][1] = MFMA16(Ah1, Bl1, acc[1][1]);
    }
    if (++jb == 3) { jb = 0; ++d; }
  }
  const int l15 = lane & 15, l4 = (lane >> 4) * 4;
  const int gb = b0 + bl;
  const size_t xbase = ((size_t)(gb * 12 + lt)) * NN;
  const size_t c1 = ((size_t)(lt * 16 + gb)) * 2;
#pragma unroll
  for (int mi = 0; mi < 2; ++mi) {
    float rhv[2][4];
#pragma unroll
    for (int r = 0; r < 4; ++r) {
      const int Rl = wr * 32 + mi * 16 + l4 + r;
      const int n = n0 + Rl;
      const size_t R = (size_t)R0 + Rl;
      const float x0a = x[(xbase + n) * 2 + 0];
      const float x0b = x[(xbase + n) * 2 + 1];
      const float x1a = X1t[c1 * NN + n];
      const float x1b = X1t[(c1 + 1) * NN + n];
      const float x2a = X2t[c1 * NN + n];
      const float x2b = X2t[(c1 + 1) * NN + n];
      const float* wx = Wx + (size_t)n * 768;
#pragma unroll
      for (int ni = 0; ni < 2; ++ni) {
        const int o = wc * 32 + ni * 16 + l15;
        float pre = acc[mi][ni][r] + bgv[(size_t)n * 128 + o]
                  + x0a * wx[o]       + x0b * wx[128 + o]
                  + x1a * wx[256 + o] + x1b * wx[384 + o]
                  + x2a * wx[512 + o] + x2b * wx[640 + o];
        const float g = 1.f / (1.f + expf(-pre));
        if (wc < 2) {                       // o < 64: r-gate -> rh
          const float rh = g * xs[R * 192 + o];
          RHs[R * 64 + o] = rh;
          rhv[ni][r] = rh;
        } else {                            // o >= 64: u-gate
          ubuf[R * 64 + (o - 64)] = g;
        }
      }
    }
    if (wc < 2) {
      const int nb = n0 + wr * 32 + mi * 16 + l4;
#pragma unroll
      for (int ni = 0; ni < 2; ++ni) {
        const int o = wc * 32 + ni * 16 + l15;
        v4h ph, pl;
#pragma unroll
        for (int r = 0; r < 4; ++r) {
          h16 hh = (h16)rhv[ni][r];
          ph[r] = hh;
          pl[r] = (h16)(rhv[ni][r] - (float)hh);
        }
        *(v4h*)(HRh + (size_t)(bl * 64 + o) * 2048 + nb) = ph;
        *(v4h*)(HRl + (size_t)(bl * 64 + o) * 2048 + nb) = pl;
      }
    }
  }
}

// ---------------- MFMA cand + GRU update ----------------
// BM=64, BN=64; 256 thr, 4 waves 2x2, wave 32x32.
__global__ __launch_bounds__(256) void mcand_k(
    float* __restrict__ xs, const float* __restrict__ RHs,
    const h16* __restrict__ Bh, const h16* __restrict__ Bl,
    const float* __restrict__ E, const float* __restrict__ bcv,
    const float* __restrict__ Wx, const float* __restrict__ x,
    const float* __restrict__ X1t, const float* __restrict__ X2t,
    const float* __restrict__ ubuf, h16* __restrict__ HRh, h16* __restrict__ HRl,
    float* __restrict__ out, int lt, int b0) {
  const int R0 = blockIdx.x * 64;
  const int bl = R0 >> 11, n0 = R0 & 2047;
  __shared__ __align__(16) h16 sAh[64 * LP], sAl[64 * LP];
  __shared__ __align__(16) h16 sBh[64 * LP], sBl[64 * LP];
  const int tid = threadIdx.x, lane = tid & 63, w = tid >> 6;
  const int wr = w >> 1, wc = w & 1;
  v4f acc[2][2] = {};
  const int asr = tid >> 2, asc = (tid & 3) * 16;  // 64 rows x 16 f32
  int d = 0, jb = 0;
  for (int t = 0; t < 30; ++t) {
    const float e = E[(size_t)(n0 + asr) * 10 + d];
    const float* src = (jb == 0) ? (RHs + (size_t)(R0 + asr) * 64 + asc)
                                 : (xs + (size_t)(R0 + asr) * 192 + jb * 64 + asc);
    v4f a0 = *(const v4f*)src;
    v4f a1 = *(const v4f*)(src + 4);
    v4f a2 = *(const v4f*)(src + 8);
    v4f a3 = *(const v4f*)(src + 12);
    v8h ah0, al0, ah1, al1;
#pragma unroll
    for (int q = 0; q < 4; ++q) {
      float v = a0[q] * e; h16 hh = (h16)v; ah0[q] = hh; al0[q] = (h16)(v - (float)hh);
      v = a1[q] * e; hh = (h16)v; ah0[4 + q] = hh; al0[4 + q] = (h16)(v - (float)hh);
      v = a2[q] * e; hh = (h16)v; ah1[q] = hh; al1[q] = (h16)(v - (float)hh);
      v = a3[q] * e; hh = (h16)v; ah1[4 + q] = hh; al1[4 + q] = (h16)(v - (float)hh);
    }
    v8h wh0 = *(const v8h*)(Bh + (size_t)asr * 1920 + t * 64 + asc);
    v8h wh1 = *(const v8h*)(Bh + (size_t)asr * 1920 + t * 64 + asc + 8);
    v8h wl0 = *(const v8h*)(Bl + (size_t)asr * 1920 + t * 64 + asc);
    v8h wl1 = *(const v8h*)(Bl + (size_t)asr * 1920 + t * 64 + asc + 8);
    __syncthreads();
    *(v8h*)(sAh + asr * LP + asc) = ah0;
    *(v8h*)(sAh + asr * LP + asc + 8) = ah1;
    *(v8h*)(sAl + asr * LP + asc) = al0;
    *(v8h*)(sAl + asr * LP + asc + 8) = al1;
    *(v8h*)(sBh + asr * LP + asc) = wh0;
    *(v8h*)(sBh + asr * LP + asc + 8) = wh1;
    *(v8h*)(sBl + asr * LP + asc) = wl0;
    *(v8h*)(sBl + asr * LP + asc + 8) = wl1;
    __syncthreads();
#pragma unroll
    for (int kk = 0; kk < 2; ++kk) {
      const int ko = kk * 32 + (lane >> 4) * 8;
      const int rs = lane & 15;
      v8h Ah0 = *(const v8h*)(sAh + (wr * 32 + rs) * LP + ko);
      v8h Ah1 = *(const v8h*)(sAh + (wr * 32 + 16 + rs) * LP + ko);
      v8h Al0 = *(const v8h*)(sAl + (wr * 32 + rs) * LP + ko);
      v8h Al1 = *(const v8h*)(sAl + (wr * 32 + 16 + rs) * LP + ko);
      v8h Bh0 = *(const v8h*)(sBh + (wc * 32 + rs) * LP + ko);
      v8h Bh1 = *(const v8h*)(sBh + (wc * 32 + 16 + rs) * LP + ko);
      v8h Bl0 = *(const v8h*)(sBl + (wc * 32 + rs) * LP + ko);
      v8h Bl1 = *(const v8h*)(sBl + (wc * 32 + 16 + rs) * LP + ko);
      acc[0][0] = MFMA16(Ah0, Bh0, acc[0][0]);
      acc[0][1] = MFMA16(Ah0, Bh1, acc[0][1]);
      acc[1][0] = MFMA16(Ah1, Bh0, acc[1][0]);
      acc[1][1] = MFMA16(Ah1, Bh1, acc[1][1]);
      acc[0][0] = MFMA16(Al0, Bh0, acc[0][0]);
      acc[0][1] = MFMA16(Al0, Bh1, acc[0][1]);
      acc[1][0] = MFMA16(Al1, Bh0, acc[1][0]);
      acc[1][1] = MFMA16(Al1, Bh1, acc[1][1]);
      acc[0][0] = MFMA16(Ah0, Bl0, acc[0][0]);
      acc[0][1] = MFMA16(Ah0, Bl1, acc[0][1]);
      acc[1][0] = MFMA16(Ah1, Bl0, acc[1][0]);
      acc[1][1] = MFMA16(Ah1, Bl1, acc[1][1]);
    }
    if (++jb == 3) { jb = 0; ++d; }
  }
  const int l15 = lane & 15, l4 = (lane >> 4) * 4;
  const int gb = b0 + bl;
  const size_t xbase = ((size_t)(gb * 12 + lt)) * NN;
  const size_t c1 = ((size_t)(lt * 16 + gb)) * 2;
#pragma unroll
  for (int mi = 0; mi < 2; ++mi) {
    float hnv[2][4];
#pragma unroll
    for (int r = 0; r < 4; ++r) {
      const int Rl = wr * 32 + mi * 16 + l4 + r;
      const int n = n0 + Rl;
      const size_t R = (size_t)R0 + Rl;
      const float x0a = x[(xbase + n) * 2 + 0];
      const float x0b = x[(xbase + n) * 2 + 1];
      const float x1a = X1t[c1 * NN + n];
      const float x1b = X1t[(c1 + 1) * NN + n];
      const float x2a = X2t[c1 * NN + n];
      const float x2b = X2t[(c1 + 1) * NN + n];
      const float* wx = Wx + (size_t)n * 384;
#pragma unroll
      for (int ni = 0; ni < 2; ++ni) {
        const int o = wc * 32 + ni * 16 + l15;
        float pre = acc[mi][ni][r] + bcv[(size_t)n * 64 + o]
                  + x0a * wx[o]       + x0b * wx[64 + o]
                  + x1a * wx[128 + o] + x1b * wx[192 + o]
                  + x2a * wx[256 + o] + x2b * wx[320 + o];
        const float cv = tanhf(pre);
        const float u = ubuf[R * 64 + o];
        const float hold = xs[R * 192 + o];
        const float hn = u * hold + (1.f - u) * cv;
        hnv[ni][r] = hn;
        xs[R * 192 + o] = hn;
        out[(xbase + n) * 64 + o] = hn;
      }
    }
    const int nb = n0 + wr * 32 + mi * 16 + l4;
#pragma unroll
    for (int ni = 0; ni < 2; ++ni) {
      const int o = wc * 32 + ni * 16 + l15;
      v4h ph, pl;
#pragma unroll
      for (int r = 0; r < 4; ++r) {
        h16 hh = (h16)hnv[ni][r];
        ph[r] = hh;
        pl[r] = (h16)(hnv[ni][r] - (float)hh);
      }
      *(v4h*)(HRh + (size_t)(bl * 64 + o) * 2048 + nb) = ph;
      *(v4h*)(HRl + (size_t)(bl * 64 + o) * 2048 + nb) = pl;
    }
  }
}

// ---------------- h_n gather: xs slot0 -> out ----------------
__global__ void hn_gather_k(const float* __restrict__ xs, float* __restrict__ dst) {
  int i = blockIdx.x * 256 + threadIdx.x;   // 1,048,576
  dst[i] = xs[(size_t)(i >> 6) * 192 + (i & 63)];
}

// ---------------- launch ----------------
extern "C" void kernel_launch(void* const* d_in, const int* in_sizes, int n_in,
                              void* d_out, int out_size, void* d_ws, size_t ws_size,
                              hipStream_t stream) {
  float* out = (float*)d_out;

  const bool in_ok = (n_in == 7) &&
      in_sizes[0] == 786432 && in_sizes[1] == 20480 && in_sizes[2] == 4194304 &&
      in_sizes[3] == 253440 && in_sizes[4] == 1280 &&
      in_sizes[5] == 126720 && in_sizes[6] == 640 && out_size == 27262976;
  if (!in_ok) {
    fill_k<<<(out_size + 255) / 256, 256, 0, stream>>>(out, 77.0f, (size_t)out_size);
    return;
  }
  constexpr size_t NEED = 60719104;
  if (ws_size < NEED) {
    fill_k<<<106496, 256, 0, stream>>>(out, 42.0f, 27262976);
    return;
  }

  const float* x   = (const float*)d_in[0];
  const float* E   = (const float*)d_in[1];
  const float* A   = (const float*)d_in[2];
  const float* Wgp = (const float*)d_in[3];
  const float* bgp = (const float*)d_in[4];
  const float* Wcp = (const float*)d_in[5];
  const float* bcp = (const float*)d_in[6];

  char* p = (char*)d_ws;
  auto carve = [&](size_t bytes) { char* r = p; p += bytes; return r; };
  // shared (35,553,280 B)
  h16*   Ah   = (h16*)carve(8388608);    // A*2048 split hi [2048][2048]
  h16*   Al   = (h16*)carve(8388608);
  float* X1t  = (float*)carve(3145728);  // A@x   [384][2048] fp32
  float* X2t  = (float*)carve(3145728);  // A@(A@x)
  h16*   WgTh = (h16*)carve(491520);     // folded gate W, transposed split [128][1920]
  h16*   WgTl = (h16*)carve(491520);
  h16*   WcTh = (h16*)carve(245760);     // [64][1920]
  h16*   WcTl = (h16*)carve(245760);
  float* WxG  = (float*)carve(6291456);  // [2048][6][128]
  float* WxC  = (float*)carve(3145728);  // [2048][6][64]
  float* bgv  = (float*)carve(1048576);
  float* bcv  = (float*)carve(524288);
  // loop scratch (25,165,824 B) -> total exactly 60,719,104
  float* xs   = (float*)carve(12582912); // [16384][192] fp32: [h | y1 | y2]
  h16*   HRh  = (h16*)carve(2097152);    // h / rh split, feature-major [512][2048]
  h16*   HRl  = (h16*)carve(2097152);
  h16*   y1h  = (h16*)carve(2097152);    // y1 split feature-major
  h16*   y1l  = (h16*)carve(2097152);
  float* ubuf = (float*)carve(4194304);  // u fp32 [16384][64]
  // rh fp32 node-major lives in d_out's h_n region (dead until the end)
  float* RHs = out + 25165824;           // 4,194,304 B
  // prep-phase aliases inside xs (dead before the half loops)
  h16* X0h = (h16*)xs;
  h16* X0l = (h16*)((char*)xs + 1572864);
  h16* X1h = (h16*)((char*)xs + 3145728);
  h16* X1l = (h16*)((char*)xs + 4718592);

  prep_Asplit_k<<<16384, 256, 0, stream>>>(A, Ah, Al);
  prep_wts_k<128><<<960, 256, 0, stream>>>(Wgp, WgTh, WgTl);
  prep_wts_k<64><<<480, 256, 0, stream>>>(Wcp, WcTh, WcTl);
  prep_wx_k<128><<<6144, 256, 0, stream>>>(E, Wgp, WxG);
  prep_wx_k<64><<<3072, 256, 0, stream>>>(E, Wcp, WxC);
  prep_b_k<128><<<1024, 256, 0, stream>>>(E, bgp, bgv);
  prep_b_k<64><<<512, 256, 0, stream>>>(E, bcp, bcv);
  prep_x0split_k<<<3072, 256, 0, stream>>>(x, X0h, X0l);
  sgemm_k<3><<<dim3(6, 32), 512, 0, stream>>>(X0h, X0l, Ah, Al, X1t, X1h, X1l, nullptr, 0);
  sgemm_k<1><<<dim3(6, 32), 512, 0, stream>>>(X1h, X1l, Ah, Al, X2t, nullptr, nullptr, nullptr, 0);

  // halves in order {1, 0} so the final hn writes land after RHs scratch dies
  for (int hf = 0; hf < 2; ++hf) {
    const int b0 = (hf == 0) ? 8 : 0;
    hipMemsetAsync(xs, 0, 12582912, stream);
    hipMemsetAsync(HRh, 0, 2097152, stream);
    hipMemsetAsync(HRl, 0, 2097152, stream);
    for (int lt = 0; lt < 12; ++lt) {
      sgemm_k<6><<<dim3(8, 32), 512, 0, stream>>>(HRh, HRl, Ah, Al, nullptr, y1h, y1l, xs, 64);
      sgemm_k<4><<<dim3(8, 32), 512, 0, stream>>>(y1h, y1l, Ah, Al, nullptr, nullptr, nullptr, xs, 128);
      mgate_k<<<256, 512, 0, stream>>>(xs, WgTh, WgTl, E, bgv, WxG, x, X1t, X2t,
                                       RHs, ubuf, HRh, HRl, lt, b0);
      sgemm_k<6><<<dim3(8, 32), 512, 0, stream>>>(HRh, HRl, Ah, Al, nullptr, y1h, y1l, xs, 64);
      sgemm_k<4><<<dim3(8, 32), 512, 0, stream>>>(y1h, y1l, Ah, Al, nullptr, nullptr, nullptr, xs, 128);
      mcand_k<<<256, 256, 0, stream>>>(xs, RHs, WcTh, WcTl, E, bcv, WxC, x, X1t, X2t,
                                       ubuf, HRh, HRl, out, lt, b0);
    }
    hn_gather_k<<<4096, 256, 0, stream>>>(xs, out + 25165824 + (size_t)b0 * 131072);
  }
}

// Round 9
// 4979.172 us; speedup vs baseline: 12.9872x; 1.0640x over previous
//
#include <hip/hip_runtime.h>
#include <cstdint>
#include <cstddef>

typedef _Float16 h16;
typedef h16 v8h __attribute__((ext_vector_type(8)));
typedef h16 v4h __attribute__((ext_vector_type(4)));
typedef float v4f __attribute__((ext_vector_type(4)));

constexpr int NN = 2048;
constexpr float INV_N = 1.0f / 2048.0f;
constexpr int LP = 72;  // LDS row stride in halves (64 + 8 pad)

#define MFMA16(a, b, c) __builtin_amdgcn_mfma_f32_16x16x32_f16((a), (b), (c), 0, 0, 0)

// ---------------- diagnostic fill ----------------
__global__ void fill_k(float* __restrict__ o, float v, size_t ntot) {
  size_t i = (size_t)blockIdx.x * 256 + threadIdx.x;
  if (i < ntot) o[i] = v;
}

// ---------------- prep kernels (unchanged from r8) ----------------

__global__ void prep_Asplit_k(const float* __restrict__ A,
                              h16* __restrict__ hi, h16* __restrict__ lo) {
  int tid = blockIdx.x * 256 + threadIdx.x;   // 4M
  float v = A[tid] * 2048.0f;
  h16 h = (h16)v;
  hi[tid] = h;
  lo[tid] = (h16)(v - (float)h);
}

__global__ void prep_x0split_k(const float* __restrict__ x,
                               h16* __restrict__ hi, h16* __restrict__ lo) {
  int tid = blockIdx.x * 256 + threadIdx.x;   // 384*2048
  int n = tid & 2047, c = tid >> 11;
  int ii = c & 1, b = (c >> 1) & 15, lt = c >> 5;
  float v = x[(((size_t)(b * 12 + lt)) * NN + n) * 2 + ii];
  h16 h = (h16)v;
  hi[tid] = h;
  lo[tid] = (h16)(v - (float)h);
}

template<int CO>
__global__ void prep_wts_k(const float* __restrict__ Wp,
                           h16* __restrict__ WTh, h16* __restrict__ WTl) {
  int tid = blockIdx.x * 256 + threadIdx.x;   // CO*1920
  int kk = tid % 1920, o = tid / 1920;
  int d = kk / 192, rem = kk - d * 192;
  int jb = rem >> 6, i = rem & 63;
  float v;
  if (jb == 0)
    v = Wp[((size_t)((d * 3 + 0) * 66 + i)) * CO + o] -
        Wp[((size_t)((d * 3 + 2) * 66 + i)) * CO + o];
  else if (jb == 1)
    v = Wp[((size_t)((d * 3 + 1) * 66 + i)) * CO + o];
  else
    v = 2.f * Wp[((size_t)((d * 3 + 2) * 66 + i)) * CO + o];
  h16 h = (h16)v;
  WTh[tid] = h;
  WTl[tid] = (h16)(v - (float)h);
}

template<int CO>
__global__ void prep_wx_k(const float* __restrict__ E, const float* __restrict__ Wp,
                          float* __restrict__ Wx) {
  int tid = blockIdx.x * 256 + threadIdx.x;   // 2048*6*CO
  int o = tid & (CO - 1), t6 = (tid / CO) % 6, n = tid / (6 * CO);
  int k = t6 >> 1, ii = t6 & 1;
  float s = 0.f;
  for (int d = 0; d < 10; ++d) {
    float p0 = Wp[((size_t)((d * 3 + 0) * 66 + 64 + ii)) * CO + o];
    float p1 = Wp[((size_t)((d * 3 + 1) * 66 + 64 + ii)) * CO + o];
    float p2 = Wp[((size_t)((d * 3 + 2) * 66 + 64 + ii)) * CO + o];
    float v = (k == 0) ? (p0 - p2) : (k == 1 ? p1 : 2.f * p2);
    s += E[n * 10 + d] * v;
  }
  Wx[tid] = s;
}

template<int CO>
__global__ void prep_b_k(const float* __restrict__ E, const float* __restrict__ bp,
                         float* __restrict__ bv) {
  int tid = blockIdx.x * 256 + threadIdx.x;   // 2048*CO
  int o = tid & (CO - 1), n = tid / CO;
  float s = 0.f;
  for (int d = 0; d < 10; ++d) s += E[n * 10 + d] * bp[d * CO + o];
  bv[tid] = s;
}

// ---------------- split-fp16 MFMA SpMM, BM=32/BN=64, 256 thr (2 blocks/CU) ----------------
// out[c][n] = INV_N * sum_m (Ih+Il)[c][m] * (Bh+Bl)[n][m]   (3-product split)
// OM bit0: oF fp32 feature; bit1: oH/oL split feature; bit2: xs scatter @xoff.
template<int OM>
__global__ __launch_bounds__(256) void sgemm_k(
    const h16* __restrict__ Ih, const h16* __restrict__ Il,
    const h16* __restrict__ Bh, const h16* __restrict__ Bl,
    float* __restrict__ oF, h16* __restrict__ oH, h16* __restrict__ oL,
    float* __restrict__ xsv, int xoff) {
  const int m0 = blockIdx.x * 32, n0 = blockIdx.y * 64;
  __shared__ __align__(16) h16 sAh[32 * LP], sAl[32 * LP];
  __shared__ __align__(16) h16 sBh[64 * LP], sBl[64 * LP];
  const int tid = threadIdx.x, lane = tid & 63, w = tid >> 6;
  v4f acc[2] = {};
  const int sr = tid >> 3, sc = (tid & 7) * 8;
  v8h rah  = *(const v8h*)(Ih + (size_t)(m0 + sr) * NN + sc);
  v8h ral  = *(const v8h*)(Il + (size_t)(m0 + sr) * NN + sc);
  v8h rb0h = *(const v8h*)(Bh + (size_t)(n0 + sr) * NN + sc);
  v8h rb0l = *(const v8h*)(Bl + (size_t)(n0 + sr) * NN + sc);
  v8h rb1h = *(const v8h*)(Bh + (size_t)(n0 + 32 + sr) * NN + sc);
  v8h rb1l = *(const v8h*)(Bl + (size_t)(n0 + 32 + sr) * NN + sc);
  for (int kt = 0; kt < NN; kt += 64) {
    __syncthreads();
    *(v8h*)(sAh + sr * LP + sc) = rah;
    *(v8h*)(sAl + sr * LP + sc) = ral;
    *(v8h*)(sBh + sr * LP + sc) = rb0h;
    *(v8h*)(sBl + sr * LP + sc) = rb0l;
    *(v8h*)(sBh + (32 + sr) * LP + sc) = rb1h;
    *(v8h*)(sBl + (32 + sr) * LP + sc) = rb1l;
    __syncthreads();
    if (kt + 64 < NN) {
      const int k2 = kt + 64 + sc;
      rah  = *(const v8h*)(Ih + (size_t)(m0 + sr) * NN + k2);
      ral  = *(const v8h*)(Il + (size_t)(m0 + sr) * NN + k2);
      rb0h = *(const v8h*)(Bh + (size_t)(n0 + sr) * NN + k2);
      rb0l = *(const v8h*)(Bl + (size_t)(n0 + sr) * NN + k2);
      rb1h = *(const v8h*)(Bh + (size_t)(n0 + 32 + sr) * NN + k2);
      rb1l = *(const v8h*)(Bl + (size_t)(n0 + 32 + sr) * NN + k2);
    }
#pragma unroll
    for (int kk = 0; kk < 2; ++kk) {
      const int ko = kk * 32 + (lane >> 4) * 8;
      const int rs = lane & 15;
      v8h a0h = *(const v8h*)(sAh + rs * LP + ko);
      v8h a1h = *(const v8h*)(sAh + (16 + rs) * LP + ko);
      v8h a0l = *(const v8h*)(sAl + rs * LP + ko);
      v8h a1l = *(const v8h*)(sAl + (16 + rs) * LP + ko);
      v8h b0h = *(const v8h*)(sBh + (w * 16 + rs) * LP + ko);
      v8h b0l = *(const v8h*)(sBl + (w * 16 + rs) * LP + ko);
      acc[0] = MFMA16(a0h, b0h, acc[0]);
      acc[1] = MFMA16(a1h, b0h, acc[1]);
      acc[0] = MFMA16(a0l, b0h, acc[0]);
      acc[1] = MFMA16(a1l, b0h, acc[1]);
      acc[0] = MFMA16(a0h, b0l, acc[0]);
      acc[1] = MFMA16(a1h, b0l, acc[1]);
    }
  }
  const int l15 = lane & 15, l4 = (lane >> 4) * 4;
  const int n = n0 + w * 16 + l15;
#pragma unroll
  for (int mi = 0; mi < 2; ++mi) {
    const int cb = m0 + mi * 16 + l4;
    float vv[4];
#pragma unroll
    for (int r = 0; r < 4; ++r) {
      vv[r] = acc[mi][r] * INV_N;
      if constexpr (OM & 1) oF[(size_t)(cb + r) * NN + n] = vv[r];
      if constexpr (OM & 2) {
        h16 h = (h16)vv[r];
        oH[(size_t)(cb + r) * NN + n] = h;
        oL[(size_t)(cb + r) * NN + n] = (h16)(vv[r] - (float)h);
      }
    }
    if constexpr (OM & 4) {
      v4f pv = {vv[0], vv[1], vv[2], vv[3]};
      *(v4f*)(xsv + ((size_t)(cb >> 6) * 2048 + n) * 192 + xoff + (cb & 63)) = pv;
    }
  }
}

// ---------------- MFMA gate: BM=32/BN=128, 256 thr, prefetch, 4-product ----------------
__global__ __launch_bounds__(256) void mgate_k(
    const float* __restrict__ xs, const h16* __restrict__ Bh, const h16* __restrict__ Bl,
    const float* __restrict__ E, const float* __restrict__ bgv,
    const float* __restrict__ Wx, const float* __restrict__ x,
    const float* __restrict__ X1t, const float* __restrict__ X2t,
    float* __restrict__ RHs, float* __restrict__ ubuf,
    h16* __restrict__ HRh, h16* __restrict__ HRl, int lt, int b0) {
  const int R0 = blockIdx.x * 32;
  const int bl = R0 >> 11, n0 = R0 & 2047;
  __shared__ __align__(16) h16 sAh[32 * LP], sAl[32 * LP];
  __shared__ __align__(16) h16 sBh[128 * LP], sBl[128 * LP];
  const int tid = threadIdx.x, lane = tid & 63, w = tid >> 6;
  v4f acc[2][2] = {};
  const int asr = tid >> 3, asc = (tid & 7) * 8;   // A: 32 rows x 8 f32
  const int bsr = tid >> 1, bso = (tid & 1) * 32;  // B: 128 rows x 32 h16
  const float* arow = xs + (size_t)(R0 + asr) * 192 + asc;
  const float* erow = E + (size_t)(n0 + asr) * 10;
  const h16* bhrow = Bh + (size_t)bsr * 1920 + bso;
  const h16* blrow = Bl + (size_t)bsr * 1920 + bso;
  v8h ah, al, pbh[4], pbl[4];
  auto load_t = [&](int t, int d, int jb) {
    const float e = erow[d];
    v4f a0 = *(const v4f*)(arow + jb * 64);
    v4f a1 = *(const v4f*)(arow + jb * 64 + 4);
#pragma unroll
    for (int q = 0; q < 4; ++q) {
      float v = a0[q] * e; h16 hh = (h16)v; ah[q] = hh; al[q] = (h16)(v - (float)hh);
      v = a1[q] * e; hh = (h16)v; ah[4 + q] = hh; al[4 + q] = (h16)(v - (float)hh);
    }
#pragma unroll
    for (int c = 0; c < 4; ++c) {
      pbh[c] = *(const v8h*)(bhrow + t * 64 + c * 8);
      pbl[c] = *(const v8h*)(blrow + t * 64 + c * 8);
    }
  };
  load_t(0, 0, 0);
  int d = 0, jb = 0;
  for (int t = 0; t < 30; ++t) {
    __syncthreads();
    *(v8h*)(sAh + asr * LP + asc) = ah;
    *(v8h*)(sAl + asr * LP + asc) = al;
#pragma unroll
    for (int c = 0; c < 4; ++c) {
      *(v8h*)(sBh + bsr * LP + bso + c * 8) = pbh[c];
      *(v8h*)(sBl + bsr * LP + bso + c * 8) = pbl[c];
    }
    __syncthreads();
    int dn = d, jn = jb + 1;
    if (jn == 3) { jn = 0; ++dn; }
    if (t < 29) load_t(t + 1, dn, jn);
#pragma unroll
    for (int kk = 0; kk < 2; ++kk) {
      const int ko = kk * 32 + (lane >> 4) * 8;
      const int rs = lane & 15;
      v8h Ah0 = *(const v8h*)(sAh + rs * LP + ko);
      v8h Ah1 = *(const v8h*)(sAh + (16 + rs) * LP + ko);
      v8h Al0 = *(const v8h*)(sAl + rs * LP + ko);
      v8h Al1 = *(const v8h*)(sAl + (16 + rs) * LP + ko);
      v8h Bh0 = *(const v8h*)(sBh + (w * 32 + rs) * LP + ko);
      v8h Bh1 = *(const v8h*)(sBh + (w * 32 + 16 + rs) * LP + ko);
      v8h Bl0 = *(const v8h*)(sBl + (w * 32 + rs) * LP + ko);
      v8h Bl1 = *(const v8h*)(sBl + (w * 32 + 16 + rs) * LP + ko);
      acc[0][0] = MFMA16(Ah0, Bh0, acc[0][0]);
      acc[0][1] = MFMA16(Ah0, Bh1, acc[0][1]);
      acc[1][0] = MFMA16(Ah1, Bh0, acc[1][0]);
      acc[1][1] = MFMA16(Ah1, Bh1, acc[1][1]);
      acc[0][0] = MFMA16(Al0, Bh0, acc[0][0]);
      acc[0][1] = MFMA16(Al0, Bh1, acc[0][1]);
      acc[1][0] = MFMA16(Al1, Bh0, acc[1][0]);
      acc[1][1] = MFMA16(Al1, Bh1, acc[1][1]);
      acc[0][0] = MFMA16(Ah0, Bl0, acc[0][0]);
      acc[0][1] = MFMA16(Ah0, Bl1, acc[0][1]);
      acc[1][0] = MFMA16(Ah1, Bl0, acc[1][0]);
      acc[1][1] = MFMA16(Ah1, Bl1, acc[1][1]);
      acc[0][0] = MFMA16(Al0, Bl0, acc[0][0]);
      acc[0][1] = MFMA16(Al0, Bl1, acc[0][1]);
      acc[1][0] = MFMA16(Al1, Bl0, acc[1][0]);
      acc[1][1] = MFMA16(Al1, Bl1, acc[1][1]);
    }
    d = dn; jb = jn;
  }
  const int l15 = lane & 15, l4 = (lane >> 4) * 4;
  const int gb = b0 + bl;
  const size_t xbase = ((size_t)(gb * 12 + lt)) * NN;
  const size_t c1 = ((size_t)(lt * 16 + gb)) * 2;
#pragma unroll
  for (int mi = 0; mi < 2; ++mi) {
    float rhv[2][4];
#pragma unroll
    for (int r = 0; r < 4; ++r) {
      const int Rl = mi * 16 + l4 + r;
      const int n = n0 + Rl;
      const size_t R = (size_t)R0 + Rl;
      const float x0a = x[(xbase + n) * 2 + 0];
      const float x0b = x[(xbase + n) * 2 + 1];
      const float x1a = X1t[c1 * NN + n];
      const float x1b = X1t[(c1 + 1) * NN + n];
      const float x2a = X2t[c1 * NN + n];
      const float x2b = X2t[(c1 + 1) * NN + n];
      const float* wx = Wx + (size_t)n * 768;
#pragma unroll
      for (int ni = 0; ni < 2; ++ni) {
        const int o = w * 32 + ni * 16 + l15;
        float pre = acc[mi][ni][r] + bgv[(size_t)n * 128 + o]
                  + x0a * wx[o]       + x0b * wx[128 + o]
                  + x1a * wx[256 + o] + x1b * wx[384 + o]
                  + x2a * wx[512 + o] + x2b * wx[640 + o];
        const float g = 1.f / (1.f + expf(-pre));
        if (w < 2) {                        // o < 64: r-gate -> rh
          const float rh = g * xs[R * 192 + o];
          RHs[R * 64 + o] = rh;
          rhv[ni][r] = rh;
        } else {                            // o >= 64: u-gate
          ubuf[R * 64 + (o - 64)] = g;
        }
      }
    }
    if (w < 2) {
      const int nb = n0 + mi * 16 + l4;
#pragma unroll
      for (int ni = 0; ni < 2; ++ni) {
        const int o = w * 32 + ni * 16 + l15;
        v4h ph, pl;
#pragma unroll
        for (int r = 0; r < 4; ++r) {
          h16 hh = (h16)rhv[ni][r];
          ph[r] = hh;
          pl[r] = (h16)(rhv[ni][r] - (float)hh);
        }
        *(v4h*)(HRh + (size_t)(bl * 64 + o) * 2048 + nb) = ph;
        *(v4h*)(HRl + (size_t)(bl * 64 + o) * 2048 + nb) = pl;
      }
    }
  }
}

// ---------------- MFMA cand + GRU update: BM=32/BN=64, 256 thr, prefetch, 4-product ----------------
__global__ __launch_bounds__(256) void mcand_k(
    float* __restrict__ xs, const float* __restrict__ RHs,
    const h16* __restrict__ Bh, const h16* __restrict__ Bl,
    const float* __restrict__ E, const float* __restrict__ bcv,
    const float* __restrict__ Wx, const float* __restrict__ x,
    const float* __restrict__ X1t, const float* __restrict__ X2t,
    const float* __restrict__ ubuf, h16* __restrict__ HRh, h16* __restrict__ HRl,
    float* __restrict__ out, int lt, int b0) {
  const int R0 = blockIdx.x * 32;
  const int bl = R0 >> 11, n0 = R0 & 2047;
  __shared__ __align__(16) h16 sAh[32 * LP], sAl[32 * LP];
  __shared__ __align__(16) h16 sBh[64 * LP], sBl[64 * LP];
  const int tid = threadIdx.x, lane = tid & 63, w = tid >> 6;
  v4f acc[2] = {};
  const int asr = tid >> 3, asc = (tid & 7) * 8;   // A: 32 rows x 8 f32
  const int bsr = tid >> 2, bso = (tid & 3) * 16;  // B: 64 rows x 16 h16
  const float* erow = E + (size_t)(n0 + asr) * 10;
  const h16* bhrow = Bh + (size_t)bsr * 1920 + bso;
  const h16* blrow = Bl + (size_t)bsr * 1920 + bso;
  v8h ah, al, pbh[2], pbl[2];
  auto load_t = [&](int t, int d, int jb) {
    const float e = erow[d];
    const float* src = (jb == 0) ? (RHs + (size_t)(R0 + asr) * 64 + asc)
                                 : (xs + (size_t)(R0 + asr) * 192 + jb * 64 + asc);
    v4f a0 = *(const v4f*)src;
    v4f a1 = *(const v4f*)(src + 4);
#pragma unroll
    for (int q = 0; q < 4; ++q) {
      float v = a0[q] * e; h16 hh = (h16)v; ah[q] = hh; al[q] = (h16)(v - (float)hh);
      v = a1[q] * e; hh = (h16)v; ah[4 + q] = hh; al[4 + q] = (h16)(v - (float)hh);
    }
#pragma unroll
    for (int c = 0; c < 2; ++c) {
      pbh[c] = *(const v8h*)(bhrow + t * 64 + c * 8);
      pbl[c] = *(const v8h*)(blrow + t * 64 + c * 8);
    }
  };
  load_t(0, 0, 0);
  int d = 0, jb = 0;
  for (int t = 0; t < 30; ++t) {
    __syncthreads();
    *(v8h*)(sAh + asr * LP + asc) = ah;
    *(v8h*)(sAl + asr * LP + asc) = al;
#pragma unroll
    for (int c = 0; c < 2; ++c) {
      *(v8h*)(sBh + bsr * LP + bso + c * 8) = pbh[c];
      *(v8h*)(sBl + bsr * LP + bso + c * 8) = pbl[c];
    }
    __syncthreads();
    int dn = d, jn = jb + 1;
    if (jn == 3) { jn = 0; ++dn; }
    if (t < 29) load_t(t + 1, dn, jn);
#pragma unroll
    for (int kk = 0; kk < 2; ++kk) {
      const int ko = kk * 32 + (lane >> 4) * 8;
      const int rs = lane & 15;
      v8h Ah0 = *(const v8h*)(sAh + rs * LP + ko);
      v8h Ah1 = *(const v8h*)(sAh + (16 + rs) * LP + ko);
      v8h Al0 = *(const v8h*)(sAl + rs * LP + ko);
      v8h Al1 = *(const v8h*)(sAl + (16 + rs) * LP + ko);
      v8h Bh0 = *(const v8h*)(sBh + (w * 16 + rs) * LP + ko);
      v8h Bl0 = *(const v8h*)(sBl + (w * 16 + rs) * LP + ko);
      acc[0] = MFMA16(Ah0, Bh0, acc[0]);
      acc[1] = MFMA16(Ah1, Bh0, acc[1]);
      acc[0] = MFMA16(Al0, Bh0, acc[0]);
      acc[1] = MFMA16(Al1, Bh0, acc[1]);
      acc[0] = MFMA16(Ah0, Bl0, acc[0]);
      acc[1] = MFMA16(Ah1, Bl0, acc[1]);
      acc[0] = MFMA16(Al0, Bl0, acc[0]);
      acc[1] = MFMA16(Al1, Bl0, acc[1]);
    }
    d = dn; jb = jn;
  }
  const int l15 = lane & 15, l4 = (lane >> 4) * 4;
  const int gb = b0 + bl;
  const size_t xbase = ((size_t)(gb * 12 + lt)) * NN;
  const size_t c1 = ((size_t)(lt * 16 + gb)) * 2;
  const int o = w * 16 + l15;
#pragma unroll
  for (int mi = 0; mi < 2; ++mi) {
    float hnv[4];
#pragma unroll
    for (int r = 0; r < 4; ++r) {
      const int Rl = mi * 16 + l4 + r;
      const int n = n0 + Rl;
      const size_t R = (size_t)R0 + Rl;
      const float x0a = x[(xbase + n) * 2 + 0];
      const float x0b = x[(xbase + n) * 2 + 1];
      const float x1a = X1t[c1 * NN + n];
      const float x1b = X1t[(c1 + 1) * NN + n];
      const float x2a = X2t[c1 * NN + n];
      const float x2b = X2t[(c1 + 1) * NN + n];
      const float* wx = Wx + (size_t)n * 384;
      float pre = acc[mi][r] + bcv[(size_t)n * 64 + o]
                + x0a * wx[o]       + x0b * wx[64 + o]
                + x1a * wx[128 + o] + x1b * wx[192 + o]
                + x2a * wx[256 + o] + x2b * wx[320 + o];
      const float cv = tanhf(pre);
      const float u = ubuf[R * 64 + o];
      const float hold = xs[R * 192 + o];
      const float hn = u * hold + (1.f - u) * cv;
      hnv[r] = hn;
      xs[R * 192 + o] = hn;
      out[(xbase + n) * 64 + o] = hn;
    }
    const int nb = n0 + mi * 16 + l4;
    v4h ph, pl;
#pragma unroll
    for (int r = 0; r < 4; ++r) {
      h16 hh = (h16)hnv[r];
      ph[r] = hh;
      pl[r] = (h16)(hnv[r] - (float)hh);
    }
    *(v4h*)(HRh + (size_t)(bl * 64 + o) * 2048 + nb) = ph;
    *(v4h*)(HRl + (size_t)(bl * 64 + o) * 2048 + nb) = pl;
  }
}

// ---------------- h_n gather: xs slot0 -> out ----------------
__global__ void hn_gather_k(const float* __restrict__ xs, float* __restrict__ dst) {
  int i = blockIdx.x * 256 + threadIdx.x;   // 1,048,576
  dst[i] = xs[(size_t)(i >> 6) * 192 + (i & 63)];
}

// ---------------- launch ----------------
extern "C" void kernel_launch(void* const* d_in, const int* in_sizes, int n_in,
                              void* d_out, int out_size, void* d_ws, size_t ws_size,
                              hipStream_t stream) {
  float* out = (float*)d_out;

  const bool in_ok = (n_in == 7) &&
      in_sizes[0] == 786432 && in_sizes[1] == 20480 && in_sizes[2] == 4194304 &&
      in_sizes[3] == 253440 && in_sizes[4] == 1280 &&
      in_sizes[5] == 126720 && in_sizes[6] == 640 && out_size == 27262976;
  if (!in_ok) {
    fill_k<<<(out_size + 255) / 256, 256, 0, stream>>>(out, 77.0f, (size_t)out_size);
    return;
  }
  constexpr size_t NEED = 60719104;
  if (ws_size < NEED) {
    fill_k<<<106496, 256, 0, stream>>>(out, 42.0f, 27262976);
    return;
  }

  const float* x   = (const float*)d_in[0];
  const float* E   = (const float*)d_in[1];
  const float* A   = (const float*)d_in[2];
  const float* Wgp = (const float*)d_in[3];
  const float* bgp = (const float*)d_in[4];
  const float* Wcp = (const float*)d_in[5];
  const float* bcp = (const float*)d_in[6];

  char* p = (char*)d_ws;
  auto carve = [&](size_t bytes) { char* r = p; p += bytes; return r; };
  // shared (35,553,280 B)
  h16*   Ah   = (h16*)carve(8388608);    // A*2048 split hi [2048][2048]
  h16*   Al   = (h16*)carve(8388608);
  float* X1t  = (float*)carve(3145728);  // A@x   [384][2048] fp32
  float* X2t  = (float*)carve(3145728);  // A@(A@x)
  h16*   WgTh = (h16*)carve(491520);     // folded gate W, transposed split [128][1920]
  h16*   WgTl = (h16*)carve(491520);
  h16*   WcTh = (h16*)carve(245760);     // [64][1920]
  h16*   WcTl = (h16*)carve(245760);
  float* WxG  = (float*)carve(6291456);  // [2048][6][128]
  float* WxC  = (float*)carve(3145728);  // [2048][6][64]
  float* bgv  = (float*)carve(1048576);
  float* bcv  = (float*)carve(524288);
  // loop scratch (25,165,824 B) -> total exactly 60,719,104
  float* xs   = (float*)carve(12582912); // [16384][192] fp32: [h | y1 | y2]
  h16*   HRh  = (h16*)carve(2097152);    // h / rh split, feature-major [512][2048]
  h16*   HRl  = (h16*)carve(2097152);
  h16*   y1h  = (h16*)carve(2097152);    // y1 split feature-major
  h16*   y1l  = (h16*)carve(2097152);
  float* ubuf = (float*)carve(4194304);  // u fp32 [16384][64]
  // rh fp32 node-major lives in d_out's h_n region (dead until the end)
  float* RHs = out + 25165824;           // 4,194,304 B
  // prep-phase aliases inside xs (dead before the half loops)
  h16* X0h = (h16*)xs;
  h16* X0l = (h16*)((char*)xs + 1572864);
  h16* X1h = (h16*)((char*)xs + 3145728);
  h16* X1l = (h16*)((char*)xs + 4718592);

  prep_Asplit_k<<<16384, 256, 0, stream>>>(A, Ah, Al);
  prep_wts_k<128><<<960, 256, 0, stream>>>(Wgp, WgTh, WgTl);
  prep_wts_k<64><<<480, 256, 0, stream>>>(Wcp, WcTh, WcTl);
  prep_wx_k<128><<<6144, 256, 0, stream>>>(E, Wgp, WxG);
  prep_wx_k<64><<<3072, 256, 0, stream>>>(E, Wcp, WxC);
  prep_b_k<128><<<1024, 256, 0, stream>>>(E, bgp, bgv);
  prep_b_k<64><<<512, 256, 0, stream>>>(E, bcp, bcv);
  prep_x0split_k<<<3072, 256, 0, stream>>>(x, X0h, X0l);
  sgemm_k<3><<<dim3(12, 32), 256, 0, stream>>>(X0h, X0l, Ah, Al, X1t, X1h, X1l, nullptr, 0);
  sgemm_k<1><<<dim3(12, 32), 256, 0, stream>>>(X1h, X1l, Ah, Al, X2t, nullptr, nullptr, nullptr, 0);

  // halves in order {1, 0} so the final hn writes land after RHs scratch dies
  for (int hf = 0; hf < 2; ++hf) {
    const int b0 = (hf == 0) ? 8 : 0;
    hipMemsetAsync(xs, 0, 12582912, stream);
    hipMemsetAsync(HRh, 0, 2097152, stream);
    hipMemsetAsync(HRl, 0, 2097152, stream);
    for (int lt = 0; lt < 12; ++lt) {
      sgemm_k<6><<<dim3(16, 32), 256, 0, stream>>>(HRh, HRl, Ah, Al, nullptr, y1h, y1l, xs, 64);
      sgemm_k<4><<<dim3(16, 32), 256, 0, stream>>>(y1h, y1l, Ah, Al, nullptr, nullptr, nullptr, xs, 128);
      mgate_k<<<512, 256, 0, stream>>>(xs, WgTh, WgTl, E, bgv, WxG, x, X1t, X2t,
                                       RHs, ubuf, HRh, HRl, lt, b0);
      sgemm_k<6><<<dim3(16, 32), 256, 0, stream>>>(HRh, HRl, Ah, Al, nullptr, y1h, y1l, xs, 64);
      sgemm_k<4><<<dim3(16, 32), 256, 0, stream>>>(y1h, y1l, Ah, Al, nullptr, nullptr, nullptr, xs, 128);
      mcand_k<<<512, 256, 0, stream>>>(xs, RHs, WcTh, WcTl, E, bcv, WxC, x, X1t, X2t,
                                       ubuf, HRh, HRl, out, lt, b0);
    }
    hn_gather_k<<<4096, 256, 0, stream>>>(xs, out + 25165824 + (size_t)b0 * 131072);
  }
}

// Round 12
// 4507.994 us; speedup vs baseline: 14.3446x; 1.1045x over previous
//
#include <hip/hip_runtime.h>
#include <cstdint>
#include <cstddef>

typedef _Float16 h16;
typedef h16 v8h __attribute__((ext_vector_type(8)));
typedef h16 v4h __attribute__((ext_vector_type(4)));
typedef float v4f __attribute__((ext_vector_type(4)));

constexpr int NN = 2048;
constexpr float INV_N = 1.0f / 2048.0f;
constexpr int LP = 72;  // LDS row stride in halves (64 + 8 pad)

#define MFMA16(a, b, c) __builtin_amdgcn_mfma_f32_16x16x32_f16((a), (b), (c), 0, 0, 0)

// ---------------- diagnostic fill ----------------
__global__ void fill_k(float* __restrict__ o, float v, size_t ntot) {
  size_t i = (size_t)blockIdx.x * 256 + threadIdx.x;
  if (i < ntot) o[i] = v;
}

// ---------------- prep kernels (r8-sub verbatim) ----------------

__global__ void prep_Asplit_k(const float* __restrict__ A,
                              h16* __restrict__ hi, h16* __restrict__ lo) {
  int tid = blockIdx.x * 256 + threadIdx.x;   // 4M
  float v = A[tid] * 2048.0f;
  h16 h = (h16)v;
  hi[tid] = h;
  lo[tid] = (h16)(v - (float)h);
}

__global__ void prep_x0split_k(const float* __restrict__ x,
                               h16* __restrict__ hi, h16* __restrict__ lo) {
  int tid = blockIdx.x * 256 + threadIdx.x;   // 384*2048
  int n = tid & 2047, c = tid >> 11;
  int ii = c & 1, b = (c >> 1) & 15, lt = c >> 5;
  float v = x[(((size_t)(b * 12 + lt)) * NN + n) * 2 + ii];
  h16 h = (h16)v;
  hi[tid] = h;
  lo[tid] = (h16)(v - (float)h);
}

template<int CO>
__global__ void prep_wts_k(const float* __restrict__ Wp,
                           h16* __restrict__ WTh, h16* __restrict__ WTl) {
  int tid = blockIdx.x * 256 + threadIdx.x;   // CO*1920
  int kk = tid % 1920, o = tid / 1920;
  int d = kk / 192, rem = kk - d * 192;
  int jb = rem >> 6, i = rem & 63;
  float v;
  if (jb == 0)
    v = Wp[((size_t)((d * 3 + 0) * 66 + i)) * CO + o] -
        Wp[((size_t)((d * 3 + 2) * 66 + i)) * CO + o];
  else if (jb == 1)
    v = Wp[((size_t)((d * 3 + 1) * 66 + i)) * CO + o];
  else
    v = 2.f * Wp[((size_t)((d * 3 + 2) * 66 + i)) * CO + o];
  h16 h = (h16)v;
  WTh[tid] = h;
  WTl[tid] = (h16)(v - (float)h);
}

template<int CO>
__global__ void prep_wx_k(const float* __restrict__ E, const float* __restrict__ Wp,
                          float* __restrict__ Wx) {
  int tid = blockIdx.x * 256 + threadIdx.x;   // 2048*6*CO
  int o = tid & (CO - 1), t6 = (tid / CO) % 6, n = tid / (6 * CO);
  int k = t6 >> 1, ii = t6 & 1;
  float s = 0.f;
  for (int d = 0; d < 10; ++d) {
    float p0 = Wp[((size_t)((d * 3 + 0) * 66 + 64 + ii)) * CO + o];
    float p1 = Wp[((size_t)((d * 3 + 1) * 66 + 64 + ii)) * CO + o];
    float p2 = Wp[((size_t)((d * 3 + 2) * 66 + 64 + ii)) * CO + o];
    float v = (k == 0) ? (p0 - p2) : (k == 1 ? p1 : 2.f * p2);
    s += E[n * 10 + d] * v;
  }
  Wx[tid] = s;
}

template<int CO>
__global__ void prep_b_k(const float* __restrict__ E, const float* __restrict__ bp,
                         float* __restrict__ bv) {
  int tid = blockIdx.x * 256 + threadIdx.x;   // 2048*CO
  int o = tid & (CO - 1), n = tid / CO;
  float s = 0.f;
  for (int d = 0; d < 10; ++d) s += E[n * 10 + d] * bp[d * CO + o];
  bv[tid] = s;
}

// ---------------- split-fp16 MFMA SpMM, BM=32/BN=64, 256 thr (r8-sub verbatim) ----------------
// out[c][n] = INV_N * sum_m (Ih+Il)[c][m] * (Bh+Bl)[n][m]   (3-product split)
// OM bit0: oF fp32 feature; bit1: oH/oL split feature; bit2: xs scatter @xoff.
template<int OM>
__global__ __launch_bounds__(256) void sgemm_k(
    const h16* __restrict__ Ih, const h16* __restrict__ Il,
    const h16* __restrict__ Bh, const h16* __restrict__ Bl,
    float* __restrict__ oF, h16* __restrict__ oH, h16* __restrict__ oL,
    float* __restrict__ xsv, int xoff) {
  const int m0 = blockIdx.x * 32, n0 = blockIdx.y * 64;
  __shared__ __align__(16) h16 sAh[32 * LP], sAl[32 * LP];
  __shared__ __align__(16) h16 sBh[64 * LP], sBl[64 * LP];
  const int tid = threadIdx.x, lane = tid & 63, w = tid >> 6;
  v4f acc[2] = {};
  const int sr = tid >> 3, sc = (tid & 7) * 8;
  v8h rah  = *(const v8h*)(Ih + (size_t)(m0 + sr) * NN + sc);
  v8h ral  = *(const v8h*)(Il + (size_t)(m0 + sr) * NN + sc);
  v8h rb0h = *(const v8h*)(Bh + (size_t)(n0 + sr) * NN + sc);
  v8h rb0l = *(const v8h*)(Bl + (size_t)(n0 + sr) * NN + sc);
  v8h rb1h = *(const v8h*)(Bh + (size_t)(n0 + 32 + sr) * NN + sc);
  v8h rb1l = *(const v8h*)(Bl + (size_t)(n0 + 32 + sr) * NN + sc);
  for (int kt = 0; kt < NN; kt += 64) {
    __syncthreads();
    *(v8h*)(sAh + sr * LP + sc) = rah;
    *(v8h*)(sAl + sr * LP + sc) = ral;
    *(v8h*)(sBh + sr * LP + sc) = rb0h;
    *(v8h*)(sBl + sr * LP + sc) = rb0l;
    *(v8h*)(sBh + (32 + sr) * LP + sc) = rb1h;
    *(v8h*)(sBl + (32 + sr) * LP + sc) = rb1l;
    __syncthreads();
    if (kt + 64 < NN) {
      const int k2 = kt + 64 + sc;
      rah  = *(const v8h*)(Ih + (size_t)(m0 + sr) * NN + k2);
      ral  = *(const v8h*)(Il + (size_t)(m0 + sr) * NN + k2);
      rb0h = *(const v8h*)(Bh + (size_t)(n0 + sr) * NN + k2);
      rb0l = *(const v8h*)(Bl + (size_t)(n0 + sr) * NN + k2);
      rb1h = *(const v8h*)(Bh + (size_t)(n0 + 32 + sr) * NN + k2);
      rb1l = *(const v8h*)(Bl + (size_t)(n0 + 32 + sr) * NN + k2);
    }
#pragma unroll
    for (int kk = 0; kk < 2; ++kk) {
      const int ko = kk * 32 + (lane >> 4) * 8;
      const int rs = lane & 15;
      v8h a0h = *(const v8h*)(sAh + rs * LP + ko);
      v8h a1h = *(const v8h*)(sAh + (16 + rs) * LP + ko);
      v8h a0l = *(const v8h*)(sAl + rs * LP + ko);
      v8h a1l = *(const v8h*)(sAl + (16 + rs) * LP + ko);
      v8h b0h = *(const v8h*)(sBh + (w * 16 + rs) * LP + ko);
      v8h b0l = *(const v8h*)(sBl + (w * 16 + rs) * LP + ko);
      acc[0] = MFMA16(a0h, b0h, acc[0]);
      acc[1] = MFMA16(a1h, b0h, acc[1]);
      acc[0] = MFMA16(a0l, b0h, acc[0]);
      acc[1] = MFMA16(a1l, b0h, acc[1]);
      acc[0] = MFMA16(a0h, b0l, acc[0]);
      acc[1] = MFMA16(a1h, b0l, acc[1]);
    }
  }
  const int l15 = lane & 15, l4 = (lane >> 4) * 4;
  const int n = n0 + w * 16 + l15;
#pragma unroll
  for (int mi = 0; mi < 2; ++mi) {
    const int cb = m0 + mi * 16 + l4;
    float vv[4];
#pragma unroll
    for (int r = 0; r < 4; ++r) {
      vv[r] = acc[mi][r] * INV_N;
      if constexpr (OM & 1) oF[(size_t)(cb + r) * NN + n] = vv[r];
      if constexpr (OM & 2) {
        h16 h = (h16)vv[r];
        oH[(size_t)(cb + r) * NN + n] = h;
        oL[(size_t)(cb + r) * NN + n] = (h16)(vv[r] - (float)h);
      }
    }
    if constexpr (OM & 4) {
      v4f pv = {vv[0], vv[1], vv[2], vv[3]};
      *(v4f*)(xsv + ((size_t)(cb >> 6) * 2048 + n) * 192 + xoff + (cb & 63)) = pv;
    }
  }
}

// ---------------- MFMA gate: BM=32/BN=128, 256 thr, prefetch, 4-product (r8-sub verbatim) ----------------
__global__ __launch_bounds__(256) void mgate_k(
    const float* __restrict__ xs, const h16* __restrict__ Bh, const h16* __restrict__ Bl,
    const float* __restrict__ E, const float* __restrict__ bgv,
    const float* __restrict__ Wx, const float* __restrict__ x,
    const float* __restrict__ X1t, const float* __restrict__ X2t,
    float* __restrict__ RHs, float* __restrict__ ubuf,
    h16* __restrict__ HRh, h16* __restrict__ HRl, int lt, int b0) {
  const int R0 = blockIdx.x * 32;
  const int bl = R0 >> 11, n0 = R0 & 2047;
  __shared__ __align__(16) h16 sAh[32 * LP], sAl[32 * LP];
  __shared__ __align__(16) h16 sBh[128 * LP], sBl[128 * LP];
  const int tid = threadIdx.x, lane = tid & 63, w = tid >> 6;
  v4f acc[2][2] = {};
  const int asr = tid >> 3, asc = (tid & 7) * 8;   // A: 32 rows x 8 f32
  const int bsr = tid >> 1, bso = (tid & 1) * 32;  // B: 128 rows x 32 h16
  const float* arow = xs + (size_t)(R0 + asr) * 192 + asc;
  const float* erow = E + (size_t)(n0 + asr) * 10;
  const h16* bhrow = Bh + (size_t)bsr * 1920 + bso;
  const h16* blrow = Bl + (size_t)bsr * 1920 + bso;
  v8h ah, al, pbh[4], pbl[4];
  auto load_t = [&](int t, int d, int jb) {
    const float e = erow[d];
    v4f a0 = *(const v4f*)(arow + jb * 64);
    v4f a1 = *(const v4f*)(arow + jb * 64 + 4);
#pragma unroll
    for (int q = 0; q < 4; ++q) {
      float v = a0[q] * e; h16 hh = (h16)v; ah[q] = hh; al[q] = (h16)(v - (float)hh);
      v = a1[q] * e; hh = (h16)v; ah[4 + q] = hh; al[4 + q] = (h16)(v - (float)hh);
    }
#pragma unroll
    for (int c = 0; c < 4; ++c) {
      pbh[c] = *(const v8h*)(bhrow + t * 64 + c * 8);
      pbl[c] = *(const v8h*)(blrow + t * 64 + c * 8);
    }
  };
  load_t(0, 0, 0);
  int d = 0, jb = 0;
  for (int t = 0; t < 30; ++t) {
    __syncthreads();
    *(v8h*)(sAh + asr * LP + asc) = ah;
    *(v8h*)(sAl + asr * LP + asc) = al;
#pragma unroll
    for (int c = 0; c < 4; ++c) {
      *(v8h*)(sBh + bsr * LP + bso + c * 8) = pbh[c];
      *(v8h*)(sBl + bsr * LP + bso + c * 8) = pbl[c];
    }
    __syncthreads();
    int dn = d, jn = jb + 1;
    if (jn == 3) { jn = 0; ++dn; }
    if (t < 29) load_t(t + 1, dn, jn);
#pragma unroll
    for (int kk = 0; kk < 2; ++kk) {
      const int ko = kk * 32 + (lane >> 4) * 8;
      const int rs = lane & 15;
      v8h Ah0 = *(const v8h*)(sAh + rs * LP + ko);
      v8h Ah1 = *(const v8h*)(sAh + (16 + rs) * LP + ko);
      v8h Al0 = *(const v8h*)(sAl + rs * LP + ko);
      v8h Al1 = *(const v8h*)(sAl + (16 + rs) * LP + ko);
      v8h Bh0 = *(const v8h*)(sBh + (w * 32 + rs) * LP + ko);
      v8h Bh1 = *(const v8h*)(sBh + (w * 32 + 16 + rs) * LP + ko);
      v8h Bl0 = *(const v8h*)(sBl + (w * 32 + rs) * LP + ko);
      v8h Bl1 = *(const v8h*)(sBl + (w * 32 + 16 + rs) * LP + ko);
      acc[0][0] = MFMA16(Ah0, Bh0, acc[0][0]);
      acc[0][1] = MFMA16(Ah0, Bh1, acc[0][1]);
      acc[1][0] = MFMA16(Ah1, Bh0, acc[1][0]);
      acc[1][1] = MFMA16(Ah1, Bh1, acc[1][1]);
      acc[0][0] = MFMA16(Al0, Bh0, acc[0][0]);
      acc[0][1] = MFMA16(Al0, Bh1, acc[0][1]);
      acc[1][0] = MFMA16(Al1, Bh0, acc[1][0]);
      acc[1][1] = MFMA16(Al1, Bh1, acc[1][1]);
      acc[0][0] = MFMA16(Ah0, Bl0, acc[0][0]);
      acc[0][1] = MFMA16(Ah0, Bl1, acc[0][1]);
      acc[1][0] = MFMA16(Ah1, Bl0, acc[1][0]);
      acc[1][1] = MFMA16(Ah1, Bl1, acc[1][1]);
      acc[0][0] = MFMA16(Al0, Bl0, acc[0][0]);
      acc[0][1] = MFMA16(Al0, Bl1, acc[0][1]);
      acc[1][0] = MFMA16(Al1, Bl0, acc[1][0]);
      acc[1][1] = MFMA16(Al1, Bl1, acc[1][1]);
    }
    d = dn; jb = jn;
  }
  const int l15 = lane & 15, l4 = (lane >> 4) * 4;
  const int gb = b0 + bl;
  const size_t xbase = ((size_t)(gb * 12 + lt)) * NN;
  const size_t c1 = ((size_t)(lt * 16 + gb)) * 2;
#pragma unroll
  for (int mi = 0; mi < 2; ++mi) {
    float rhv[2][4];
#pragma unroll
    for (int r = 0; r < 4; ++r) {
      const int Rl = mi * 16 + l4 + r;
      const int n = n0 + Rl;
      const size_t R = (size_t)R0 + Rl;
      const float x0a = x[(xbase + n) * 2 + 0];
      const float x0b = x[(xbase + n) * 2 + 1];
      const float x1a = X1t[c1 * NN + n];
      const float x1b = X1t[(c1 + 1) * NN + n];
      const float x2a = X2t[c1 * NN + n];
      const float x2b = X2t[(c1 + 1) * NN + n];
      const float* wx = Wx + (size_t)n * 768;
#pragma unroll
      for (int ni = 0; ni < 2; ++ni) {
        const int o = w * 32 + ni * 16 + l15;
        float pre = acc[mi][ni][r] + bgv[(size_t)n * 128 + o]
                  + x0a * wx[o]       + x0b * wx[128 + o]
                  + x1a * wx[256 + o] + x1b * wx[384 + o]
                  + x2a * wx[512 + o] + x2b * wx[640 + o];
        const float g = 1.f / (1.f + expf(-pre));
        if (w < 2) {                        // o < 64: r-gate -> rh
          const float rh = g * xs[R * 192 + o];
          RHs[R * 64 + o] = rh;
          rhv[ni][r] = rh;
        } else {                            // o >= 64: u-gate
          ubuf[R * 64 + (o - 64)] = g;
        }
      }
    }
    if (w < 2) {
      const int nb = n0 + mi * 16 + l4;
#pragma unroll
      for (int ni = 0; ni < 2; ++ni) {
        const int o = w * 32 + ni * 16 + l15;
        v4h ph, pl;
#pragma unroll
        for (int r = 0; r < 4; ++r) {
          h16 hh = (h16)rhv[ni][r];
          ph[r] = hh;
          pl[r] = (h16)(rhv[ni][r] - (float)hh);
        }
        *(v4h*)(HRh + (size_t)(bl * 64 + o) * 2048 + nb) = ph;
        *(v4h*)(HRl + (size_t)(bl * 64 + o) * 2048 + nb) = pl;
      }
    }
  }
}

// ---------------- MFMA cand + GRU update: BM=32/BN=64, 256 thr, prefetch, 4-product (r8-sub verbatim) ----------------
__global__ __launch_bounds__(256) void mcand_k(
    float* __restrict__ xs, const float* __restrict__ RHs,
    const h16* __restrict__ Bh, const h16* __restrict__ Bl,
    const float* __restrict__ E, const float* __restrict__ bcv,
    const float* __restrict__ Wx, const float* __restrict__ x,
    const float* __restrict__ X1t, const float* __restrict__ X2t,
    const float* __restrict__ ubuf, h16* __restrict__ HRh, h16* __restrict__ HRl,
    float* __restrict__ out, int lt, int b0) {
  const int R0 = blockIdx.x * 32;
  const int bl = R0 >> 11, n0 = R0 & 2047;
  __shared__ __align__(16) h16 sAh[32 * LP], sAl[32 * LP];
  __shared__ __align__(16) h16 sBh[64 * LP], sBl[64 * LP];
  const int tid = threadIdx.x, lane = tid & 63, w = tid >> 6;
  v4f acc[2] = {};
  const int asr = tid >> 3, asc = (tid & 7) * 8;   // A: 32 rows x 8 f32
  const int bsr = tid >> 2, bso = (tid & 3) * 16;  // B: 64 rows x 16 h16
  const float* erow = E + (size_t)(n0 + asr) * 10;
  const h16* bhrow = Bh + (size_t)bsr * 1920 + bso;
  const h16* blrow = Bl + (size_t)bsr * 1920 + bso;
  v8h ah, al, pbh[2], pbl[2];
  auto load_t = [&](int t, int d, int jb) {
    const float e = erow[d];
    const float* src = (jb == 0) ? (RHs + (size_t)(R0 + asr) * 64 + asc)
                                 : (xs + (size_t)(R0 + asr) * 192 + jb * 64 + asc);
    v4f a0 = *(const v4f*)src;
    v4f a1 = *(const v4f*)(src + 4);
#pragma unroll
    for (int q = 0; q < 4; ++q) {
      float v = a0[q] * e; h16 hh = (h16)v; ah[q] = hh; al[q] = (h16)(v - (float)hh);
      v = a1[q] * e; hh = (h16)v; ah[4 + q] = hh; al[4 + q] = (h16)(v - (float)hh);
    }
#pragma unroll
    for (int c = 0; c < 2; ++c) {
      pbh[c] = *(const v8h*)(bhrow + t * 64 + c * 8);
      pbl[c] = *(const v8h*)(blrow + t * 64 + c * 8);
    }
  };
  load_t(0, 0, 0);
  int d = 0, jb = 0;
  for (int t = 0; t < 30; ++t) {
    __syncthreads();
    *(v8h*)(sAh + asr * LP + asc) = ah;
    *(v8h*)(sAl + asr * LP + asc) = al;
#pragma unroll
    for (int c = 0; c < 2; ++c) {
      *(v8h*)(sBh + bsr * LP + bso + c * 8) = pbh[c];
      *(v8h*)(sBl + bsr * LP + bso + c * 8) = pbl[c];
    }
    __syncthreads();
    int dn = d, jn = jb + 1;
    if (jn == 3) { jn = 0; ++dn; }
    if (t < 29) load_t(t + 1, dn, jn);
#pragma unroll
    for (int kk = 0; kk < 2; ++kk) {
      const int ko = kk * 32 + (lane >> 4) * 8;
      const int rs = lane & 15;
      v8h Ah0 = *(const v8h*)(sAh + rs * LP + ko);
      v8h Ah1 = *(const v8h*)(sAh + (16 + rs) * LP + ko);
      v8h Al0 = *(const v8h*)(sAl + rs * LP + ko);
      v8h Al1 = *(const v8h*)(sAl + (16 + rs) * LP + ko);
      v8h Bh0 = *(const v8h*)(sBh + (w * 16 + rs) * LP + ko);
      v8h Bl0 = *(const v8h*)(sBl + (w * 16 + rs) * LP + ko);
      acc[0] = MFMA16(Ah0, Bh0, acc[0]);
      acc[1] = MFMA16(Ah1, Bh0, acc[1]);
      acc[0] = MFMA16(Al0, Bh0, acc[0]);
      acc[1] = MFMA16(Al1, Bh0, acc[1]);
      acc[0] = MFMA16(Ah0, Bl0, acc[0]);
      acc[1] = MFMA16(Ah1, Bl0, acc[1]);
      acc[0] = MFMA16(Al0, Bl0, acc[0]);
      acc[1] = MFMA16(Al1, Bl0, acc[1]);
    }
    d = dn; jb = jn;
  }
  const int l15 = lane & 15, l4 = (lane >> 4) * 4;
  const int gb = b0 + bl;
  const size_t xbase = ((size_t)(gb * 12 + lt)) * NN;
  const size_t c1 = ((size_t)(lt * 16 + gb)) * 2;
  const int o = w * 16 + l15;
#pragma unroll
  for (int mi = 0; mi < 2; ++mi) {
    float hnv[4];
#pragma unroll
    for (int r = 0; r < 4; ++r) {
      const int Rl = mi * 16 + l4 + r;
      const int n = n0 + Rl;
      const size_t R = (size_t)R0 + Rl;
      const float x0a = x[(xbase + n) * 2 + 0];
      const float x0b = x[(xbase + n) * 2 + 1];
      const float x1a = X1t[c1 * NN + n];
      const float x1b = X1t[(c1 + 1) * NN + n];
      const float x2a = X2t[c1 * NN + n];
      const float x2b = X2t[(c1 + 1) * NN + n];
      const float* wx = Wx + (size_t)n * 384;
      float pre = acc[mi][r] + bcv[(size_t)n * 64 + o]
                + x0a * wx[o]       + x0b * wx[64 + o]
                + x1a * wx[128 + o] + x1b * wx[192 + o]
                + x2a * wx[256 + o] + x2b * wx[320 + o];
      const float cv = tanhf(pre);
      const float u = ubuf[R * 64 + o];
      const float hold = xs[R * 192 + o];
      const float hn = u * hold + (1.f - u) * cv;
      hnv[r] = hn;
      xs[R * 192 + o] = hn;
      out[(xbase + n) * 64 + o] = hn;
    }
    const int nb = n0 + mi * 16 + l4;
    v4h ph, pl;
#pragma unroll
    for (int r = 0; r < 4; ++r) {
      h16 hh = (h16)hnv[r];
      ph[r] = hh;
      pl[r] = (h16)(hnv[r] - (float)hh);
    }
    *(v4h*)(HRh + (size_t)(bl * 64 + o) * 2048 + nb) = ph;
    *(v4h*)(HRl + (size_t)(bl * 64 + o) * 2048 + nb) = pl;
  }
}

// ---------------- h_n gather: xs slot0 -> out (overwrites ubuf region, last) ----------------
__global__ void hn_gather_k(const float* __restrict__ xs, float* __restrict__ dst) {
  int i = blockIdx.x * 256 + threadIdx.x;   // 2,097,152
  dst[i] = xs[(size_t)(i >> 6) * 192 + (i & 63)];
}

// ---------------- launch ----------------
extern "C" void kernel_launch(void* const* d_in, const int* in_sizes, int n_in,
                              void* d_out, int out_size, void* d_ws, size_t ws_size,
                              hipStream_t stream) {
  float* out = (float*)d_out;

  const bool in_ok = (n_in == 7) &&
      in_sizes[0] == 786432 && in_sizes[1] == 20480 && in_sizes[2] == 4194304 &&
      in_sizes[3] == 253440 && in_sizes[4] == 1280 &&
      in_sizes[5] == 126720 && in_sizes[6] == 640 && out_size == 27262976;
  if (!in_ok) {
    fill_k<<<(out_size + 255) / 256, 256, 0, stream>>>(out, 77.0f, (size_t)out_size);
    return;
  }
  constexpr size_t NEED = 85884928;   // full-batch plan (ws >= this confirmed r11-ran)
  if (ws_size < NEED) {
    fill_k<<<106496, 256, 0, stream>>>(out, 42.0f, 27262976);
    return;
  }

  const float* x   = (const float*)d_in[0];
  const float* E   = (const float*)d_in[1];
  const float* A   = (const float*)d_in[2];
  const float* Wgp = (const float*)d_in[3];
  const float* bgp = (const float*)d_in[4];
  const float* Wcp = (const float*)d_in[5];
  const float* bcp = (const float*)d_in[6];

  char* p = (char*)d_ws;
  auto carve = [&](size_t bytes) { char* r = p; p += bytes; return r; };
  // shared (35,553,280 B)
  h16*   Ah   = (h16*)carve(8388608);    // A*2048 split hi [2048][2048]
  h16*   Al   = (h16*)carve(8388608);
  float* X1t  = (float*)carve(3145728);  // A@x   [384][2048] fp32
  float* X2t  = (float*)carve(3145728);  // A@(A@x)
  h16*   WgTh = (h16*)carve(491520);     // folded gate W, transposed split [128][1920]
  h16*   WgTl = (h16*)carve(491520);
  h16*   WcTh = (h16*)carve(245760);     // [64][1920]
  h16*   WcTl = (h16*)carve(245760);
  float* WxG  = (float*)carve(6291456);  // [2048][6][128]
  float* WxC  = (float*)carve(3145728);  // [2048][6][64]
  float* bgv  = (float*)carve(1048576);
  float* bcv  = (float*)carve(524288);
  // full-batch loop scratch (50,331,648 B) -> total 85,884,928
  float* xs   = (float*)carve(25165824); // [32768][192] fp32: [h | y1 | y2]
  h16*   HRh  = (h16*)carve(4194304);    // h / rh split, feature-major [1024][2048]
  h16*   HRl  = (h16*)carve(4194304);
  h16*   y1h  = (h16*)carve(4194304);    // y1 split feature-major
  h16*   y1l  = (h16*)carve(4194304);
  float* RHs  = (float*)carve(8388608);  // r*h fp32 node-major [32768][64]
  // u gate lives in d_out's h_n region (dead until hn_gather at the very end)
  float* ubuf = out + 25165824;          // 8,388,608 B
  // prep-phase aliases inside xs (dead before the loop memset)
  h16* X0h = (h16*)xs;
  h16* X0l = (h16*)((char*)xs + 1572864);
  h16* X1h = (h16*)((char*)xs + 3145728);
  h16* X1l = (h16*)((char*)xs + 4718592);

  prep_Asplit_k<<<16384, 256, 0, stream>>>(A, Ah, Al);
  prep_wts_k<128><<<960, 256, 0, stream>>>(Wgp, WgTh, WgTl);
  prep_wts_k<64><<<480, 256, 0, stream>>>(Wcp, WcTh, WcTl);
  prep_wx_k<128><<<6144, 256, 0, stream>>>(E, Wgp, WxG);
  prep_wx_k<64><<<3072, 256, 0, stream>>>(E, Wcp, WxC);
  prep_b_k<128><<<1024, 256, 0, stream>>>(E, bgp, bgv);
  prep_b_k<64><<<512, 256, 0, stream>>>(E, bcp, bcv);
  prep_x0split_k<<<3072, 256, 0, stream>>>(x, X0h, X0l);
  sgemm_k<3><<<dim3(12, 32), 256, 0, stream>>>(X0h, X0l, Ah, Al, X1t, X1h, X1l, nullptr, 0);
  sgemm_k<1><<<dim3(12, 32), 256, 0, stream>>>(X1h, X1l, Ah, Al, X2t, nullptr, nullptr, nullptr, 0);

  hipMemsetAsync(xs, 0, 25165824, stream);
  hipMemsetAsync(HRh, 0, 4194304, stream);
  hipMemsetAsync(HRl, 0, 4194304, stream);
  for (int lt = 0; lt < 12; ++lt) {
    sgemm_k<6><<<dim3(32, 32), 256, 0, stream>>>(HRh, HRl, Ah, Al, nullptr, y1h, y1l, xs, 64);
    sgemm_k<4><<<dim3(32, 32), 256, 0, stream>>>(y1h, y1l, Ah, Al, nullptr, nullptr, nullptr, xs, 128);
    mgate_k<<<1024, 256, 0, stream>>>(xs, WgTh, WgTl, E, bgv, WxG, x, X1t, X2t,
                                      RHs, ubuf, HRh, HRl, lt, 0);
    sgemm_k<6><<<dim3(32, 32), 256, 0, stream>>>(HRh, HRl, Ah, Al, nullptr, y1h, y1l, xs, 64);
    sgemm_k<4><<<dim3(32, 32), 256, 0, stream>>>(y1h, y1l, Ah, Al, nullptr, nullptr, nullptr, xs, 128);
    mcand_k<<<1024, 256, 0, stream>>>(xs, RHs, WcTh, WcTl, E, bcv, WxC, x, X1t, X2t,
                                      ubuf, HRh, HRl, out, lt, 0);
  }
  hn_gather_k<<<8192, 256, 0, stream>>>(xs, out + 25165824);
}

// Round 13
// 4326.794 us; speedup vs baseline: 14.9453x; 1.0419x over previous
//
#include <hip/hip_runtime.h>
#include <cstdint>
#include <cstddef>

typedef _Float16 h16;
typedef h16 v8h __attribute__((ext_vector_type(8)));
typedef h16 v4h __attribute__((ext_vector_type(4)));
typedef float v4f __attribute__((ext_vector_type(4)));

constexpr int NN = 2048;
constexpr float INV_N = 1.0f / 2048.0f;
constexpr int LP = 72;  // LDS row stride in halves (64 + 8 pad)

#define MFMA16(a, b, c) __builtin_amdgcn_mfma_f32_16x16x32_f16((a), (b), (c), 0, 0, 0)

// ---------------- diagnostic fill ----------------
__global__ void fill_k(float* __restrict__ o, float v, size_t ntot) {
  size_t i = (size_t)blockIdx.x * 256 + threadIdx.x;
  if (i < ntot) o[i] = v;
}

// ---------------- prep kernels ----------------

__global__ void prep_Asplit_k(const float* __restrict__ A,
                              h16* __restrict__ hi, h16* __restrict__ lo) {
  int tid = blockIdx.x * 256 + threadIdx.x;   // 4M
  float v = A[tid] * 2048.0f;
  h16 h = (h16)v;
  hi[tid] = h;
  lo[tid] = (h16)(v - (float)h);
}

// AsT[j][t] = A[t][j]*2048, split (coalesced writes; strided reads once, L3-absorbed)
__global__ void prep_AsTsplit_k(const float* __restrict__ A,
                                h16* __restrict__ hi, h16* __restrict__ lo) {
  int tid = blockIdx.x * 256 + threadIdx.x;   // 4M
  int t = tid & 2047, j = tid >> 11;
  float v = A[(size_t)t * NN + j] * 2048.0f;
  h16 h = (h16)v;
  hi[(size_t)j * NN + t] = h;
  lo[(size_t)j * NN + t] = (h16)(v - (float)h);
}

__global__ void prep_x0split_k(const float* __restrict__ x,
                               h16* __restrict__ hi, h16* __restrict__ lo) {
  int tid = blockIdx.x * 256 + threadIdx.x;   // 384*2048
  int n = tid & 2047, c = tid >> 11;
  int ii = c & 1, b = (c >> 1) & 15, lt = c >> 5;
  float v = x[(((size_t)(b * 12 + lt)) * NN + n) * 2 + ii];
  h16 h = (h16)v;
  hi[tid] = h;
  lo[tid] = (h16)(v - (float)h);
}

template<int CO>
__global__ void prep_wts_k(const float* __restrict__ Wp,
                           h16* __restrict__ WTh, h16* __restrict__ WTl) {
  int tid = blockIdx.x * 256 + threadIdx.x;   // CO*1920
  int kk = tid % 1920, o = tid / 1920;
  int d = kk / 192, rem = kk - d * 192;
  int jb = rem >> 6, i = rem & 63;
  float v;
  if (jb == 0)
    v = Wp[((size_t)((d * 3 + 0) * 66 + i)) * CO + o] -
        Wp[((size_t)((d * 3 + 2) * 66 + i)) * CO + o];
  else if (jb == 1)
    v = Wp[((size_t)((d * 3 + 1) * 66 + i)) * CO + o];
  else
    v = 2.f * Wp[((size_t)((d * 3 + 2) * 66 + i)) * CO + o];
  h16 h = (h16)v;
  WTh[tid] = h;
  WTl[tid] = (h16)(v - (float)h);
}

template<int CO>
__global__ void prep_wx_k(const float* __restrict__ E, const float* __restrict__ Wp,
                          float* __restrict__ Wx) {
  int tid = blockIdx.x * 256 + threadIdx.x;   // 2048*6*CO
  int o = tid & (CO - 1), t6 = (tid / CO) % 6, n = tid / (6 * CO);
  int k = t6 >> 1, ii = t6 & 1;
  float s = 0.f;
  for (int d = 0; d < 10; ++d) {
    float p0 = Wp[((size_t)((d * 3 + 0) * 66 + 64 + ii)) * CO + o];
    float p1 = Wp[((size_t)((d * 3 + 1) * 66 + 64 + ii)) * CO + o];
    float p2 = Wp[((size_t)((d * 3 + 2) * 66 + 64 + ii)) * CO + o];
    float v = (k == 0) ? (p0 - p2) : (k == 1 ? p1 : 2.f * p2);
    s += E[n * 10 + d] * v;
  }
  Wx[tid] = s;
}

template<int CO>
__global__ void prep_b_k(const float* __restrict__ E, const float* __restrict__ bp,
                         float* __restrict__ bv) {
  int tid = blockIdx.x * 256 + threadIdx.x;   // 2048*CO
  int o = tid & (CO - 1), n = tid / CO;
  float s = 0.f;
  for (int d = 0; d < 10; ++d) s += E[n * 10 + d] * bp[d * CO + o];
  bv[tid] = s;
}

// ---------------- split-fp16 MFMA SpMM, BM=32/BN=64, 256 thr ----------------
// out[c][n] = INV_N * sum_m (Ih+Il)[c][m] * (Bh+Bl)[n][m]   (3-product split)
// OM bit0: oF fp32 feature; bit1: oH/oL split feature; bit2: xs scatter
// (stacked-aware: col n>=2048 -> slot xoff+64).
template<int OM>
__global__ __launch_bounds__(256) void sgemm_k(
    const h16* __restrict__ Ih, const h16* __restrict__ Il,
    const h16* __restrict__ Bh, const h16* __restrict__ Bl,
    float* __restrict__ oF, h16* __restrict__ oH, h16* __restrict__ oL,
    float* __restrict__ xsv, int xoff) {
  const int m0 = blockIdx.x * 32, n0 = blockIdx.y * 64;
  __shared__ __align__(16) h16 sAh[32 * LP], sAl[32 * LP];
  __shared__ __align__(16) h16 sBh[64 * LP], sBl[64 * LP];
  const int tid = threadIdx.x, lane = tid & 63, w = tid >> 6;
  v4f acc[2] = {};
  const int sr = tid >> 3, sc = (tid & 7) * 8;
  v8h rah  = *(const v8h*)(Ih + (size_t)(m0 + sr) * NN + sc);
  v8h ral  = *(const v8h*)(Il + (size_t)(m0 + sr) * NN + sc);
  v8h rb0h = *(const v8h*)(Bh + (size_t)(n0 + sr) * NN + sc);
  v8h rb0l = *(const v8h*)(Bl + (size_t)(n0 + sr) * NN + sc);
  v8h rb1h = *(const v8h*)(Bh + (size_t)(n0 + 32 + sr) * NN + sc);
  v8h rb1l = *(const v8h*)(Bl + (size_t)(n0 + 32 + sr) * NN + sc);
  for (int kt = 0; kt < NN; kt += 64) {
    __syncthreads();
    *(v8h*)(sAh + sr * LP + sc) = rah;
    *(v8h*)(sAl + sr * LP + sc) = ral;
    *(v8h*)(sBh + sr * LP + sc) = rb0h;
    *(v8h*)(sBl + sr * LP + sc) = rb0l;
    *(v8h*)(sBh + (32 + sr) * LP + sc) = rb1h;
    *(v8h*)(sBl + (32 + sr) * LP + sc) = rb1l;
    __syncthreads();
    if (kt + 64 < NN) {
      const int k2 = kt + 64 + sc;
      rah  = *(const v8h*)(Ih + (size_t)(m0 + sr) * NN + k2);
      ral  = *(const v8h*)(Il + (size_t)(m0 + sr) * NN + k2);
      rb0h = *(const v8h*)(Bh + (size_t)(n0 + sr) * NN + k2);
      rb0l = *(const v8h*)(Bl + (size_t)(n0 + sr) * NN + k2);
      rb1h = *(const v8h*)(Bh + (size_t)(n0 + 32 + sr) * NN + k2);
      rb1l = *(const v8h*)(Bl + (size_t)(n0 + 32 + sr) * NN + k2);
    }
#pragma unroll
    for (int kk = 0; kk < 2; ++kk) {
      const int ko = kk * 32 + (lane >> 4) * 8;
      const int rs = lane & 15;
      v8h a0h = *(const v8h*)(sAh + rs * LP + ko);
      v8h a1h = *(const v8h*)(sAh + (16 + rs) * LP + ko);
      v8h a0l = *(const v8h*)(sAl + rs * LP + ko);
      v8h a1l = *(const v8h*)(sAl + (16 + rs) * LP + ko);
      v8h b0h = *(const v8h*)(sBh + (w * 16 + rs) * LP + ko);
      v8h b0l = *(const v8h*)(sBl + (w * 16 + rs) * LP + ko);
      acc[0] = MFMA16(a0h, b0h, acc[0]);
      acc[1] = MFMA16(a1h, b0h, acc[1]);
      acc[0] = MFMA16(a0l, b0h, acc[0]);
      acc[1] = MFMA16(a1l, b0h, acc[1]);
      acc[0] = MFMA16(a0h, b0l, acc[0]);
      acc[1] = MFMA16(a1h, b0l, acc[1]);
    }
  }
  const int l15 = lane & 15, l4 = (lane >> 4) * 4;
  const int n = n0 + w * 16 + l15;
#pragma unroll
  for (int mi = 0; mi < 2; ++mi) {
    const int cb = m0 + mi * 16 + l4;
    float vv[4];
#pragma unroll
    for (int r = 0; r < 4; ++r) {
      vv[r] = acc[mi][r] * INV_N;
      if constexpr (OM & 1) oF[(size_t)(cb + r) * NN + n] = vv[r];
      if constexpr (OM & 2) {
        h16 h = (h16)vv[r];
        oH[(size_t)(cb + r) * NN + n] = h;
        oL[(size_t)(cb + r) * NN + n] = (h16)(vv[r] - (float)h);
      }
    }
    if constexpr (OM & 4) {
      const int n2 = n & 2047;
      const int xo = xoff + ((n >> 11) << 6);
      v4f pv = {vv[0], vv[1], vv[2], vv[3]};
      *(v4f*)(xsv + ((size_t)(cb >> 6) * 2048 + n2) * 192 + xo + (cb & 63)) = pv;
    }
  }
}

// ---------------- MFMA gate: BM=32, BN=64 via gridDim.y o-family split ----------------
// gy==0: o in [0,64) -> r-gate, rh writes.  gy==1: o in [64,128) -> u-gate.
__global__ __launch_bounds__(256) void mgate_k(
    const float* __restrict__ xs, const h16* __restrict__ Bh, const h16* __restrict__ Bl,
    const float* __restrict__ E, const float* __restrict__ bgv,
    const float* __restrict__ Wx, const float* __restrict__ x,
    const float* __restrict__ X1t, const float* __restrict__ X2t,
    float* __restrict__ RHs, float* __restrict__ ubuf,
    h16* __restrict__ HRh, h16* __restrict__ HRl, int lt) {
  const int R0 = blockIdx.x * 32;
  const int gy = blockIdx.y, ob = gy * 64;
  const int bl = R0 >> 11, n0 = R0 & 2047;
  __shared__ __align__(16) h16 sAh[32 * LP], sAl[32 * LP];
  __shared__ __align__(16) h16 sBh[64 * LP], sBl[64 * LP];
  const int tid = threadIdx.x, lane = tid & 63, w = tid >> 6;
  v4f acc[2] = {};
  const int asr = tid >> 3, asc = (tid & 7) * 8;   // A: 32 rows x 8 f32
  const int bsr = tid >> 2, bso = (tid & 3) * 16;  // B: 64 rows x 16 h16
  const float* arow = xs + (size_t)(R0 + asr) * 192 + asc;
  const float* erow = E + (size_t)(n0 + asr) * 10;
  const h16* bhrow = Bh + (size_t)(ob + bsr) * 1920 + bso;
  const h16* blrow = Bl + (size_t)(ob + bsr) * 1920 + bso;
  v8h ah, al, pbh[2], pbl[2];
  auto load_t = [&](int t, int d, int jb) {
    const float e = erow[d];
    v4f a0 = *(const v4f*)(arow + jb * 64);
    v4f a1 = *(const v4f*)(arow + jb * 64 + 4);
#pragma unroll
    for (int q = 0; q < 4; ++q) {
      float v = a0[q] * e; h16 hh = (h16)v; ah[q] = hh; al[q] = (h16)(v - (float)hh);
      v = a1[q] * e; hh = (h16)v; ah[4 + q] = hh; al[4 + q] = (h16)(v - (float)hh);
    }
#pragma unroll
    for (int c = 0; c < 2; ++c) {
      pbh[c] = *(const v8h*)(bhrow + t * 64 + c * 8);
      pbl[c] = *(const v8h*)(blrow + t * 64 + c * 8);
    }
  };
  load_t(0, 0, 0);
  int d = 0, jb = 0;
  for (int t = 0; t < 30; ++t) {
    __syncthreads();
    *(v8h*)(sAh + asr * LP + asc) = ah;
    *(v8h*)(sAl + asr * LP + asc) = al;
#pragma unroll
    for (int c = 0; c < 2; ++c) {
      *(v8h*)(sBh + bsr * LP + bso + c * 8) = pbh[c];
      *(v8h*)(sBl + bsr * LP + bso + c * 8) = pbl[c];
    }
    __syncthreads();
    int dn = d, jn = jb + 1;
    if (jn == 3) { jn = 0; ++dn; }
    if (t < 29) load_t(t + 1, dn, jn);
#pragma unroll
    for (int kk = 0; kk < 2; ++kk) {
      const int ko = kk * 32 + (lane >> 4) * 8;
      const int rs = lane & 15;
      v8h Ah0 = *(const v8h*)(sAh + rs * LP + ko);
      v8h Ah1 = *(const v8h*)(sAh + (16 + rs) * LP + ko);
      v8h Al0 = *(const v8h*)(sAl + rs * LP + ko);
      v8h Al1 = *(const v8h*)(sAl + (16 + rs) * LP + ko);
      v8h Bh0 = *(const v8h*)(sBh + (w * 16 + rs) * LP + ko);
      v8h Bl0 = *(const v8h*)(sBl + (w * 16 + rs) * LP + ko);
      acc[0] = MFMA16(Ah0, Bh0, acc[0]);
      acc[1] = MFMA16(Ah1, Bh0, acc[1]);
      acc[0] = MFMA16(Al0, Bh0, acc[0]);
      acc[1] = MFMA16(Al1, Bh0, acc[1]);
      acc[0] = MFMA16(Ah0, Bl0, acc[0]);
      acc[1] = MFMA16(Ah1, Bl0, acc[1]);
      acc[0] = MFMA16(Al0, Bl0, acc[0]);
      acc[1] = MFMA16(Al1, Bl0, acc[1]);
    }
    d = dn; jb = jn;
  }
  const int l15 = lane & 15, l4 = (lane >> 4) * 4;
  const size_t xbase = ((size_t)(bl * 12 + lt)) * NN;
  const size_t c1 = ((size_t)(lt * 16 + bl)) * 2;
  const int o = ob + w * 16 + l15;
#pragma unroll
  for (int mi = 0; mi < 2; ++mi) {
    float rhv[4];
#pragma unroll
    for (int r = 0; r < 4; ++r) {
      const int Rl = mi * 16 + l4 + r;
      const int n = n0 + Rl;
      const size_t R = (size_t)R0 + Rl;
      const float x0a = x[(xbase + n) * 2 + 0];
      const float x0b = x[(xbase + n) * 2 + 1];
      const float x1a = X1t[c1 * NN + n];
      const float x1b = X1t[(c1 + 1) * NN + n];
      const float x2a = X2t[c1 * NN + n];
      const float x2b = X2t[(c1 + 1) * NN + n];
      const float* wx = Wx + (size_t)n * 768;
      float pre = acc[mi][r] + bgv[(size_t)n * 128 + o]
                + x0a * wx[o]       + x0b * wx[128 + o]
                + x1a * wx[256 + o] + x1b * wx[384 + o]
                + x2a * wx[512 + o] + x2b * wx[640 + o];
      const float g = 1.f / (1.f + expf(-pre));
      if (gy == 0) {
        const float rh = g * xs[R * 192 + o];
        RHs[(size_t)bl * 1572864 + (size_t)n * 64 + o] = rh;
        rhv[r] = rh;
      } else {
        ubuf[R * 64 + (o - 64)] = g;
      }
    }
    if (gy == 0) {
      const int nb = n0 + mi * 16 + l4;
      v4h ph, pl;
#pragma unroll
      for (int r = 0; r < 4; ++r) {
        h16 hh = (h16)rhv[r];
        ph[r] = hh;
        pl[r] = (h16)(rhv[r] - (float)hh);
      }
      *(v4h*)(HRh + (size_t)(bl * 64 + o) * 2048 + nb) = ph;
      *(v4h*)(HRl + (size_t)(bl * 64 + o) * 2048 + nb) = pl;
    }
  }
}

// ---------------- MFMA cand + GRU update: BM=32/BN=64 (r12 body, RHs addr updated) ----------------
__global__ __launch_bounds__(256) void mcand_k(
    float* __restrict__ xs, const float* __restrict__ RHs,
    const h16* __restrict__ Bh, const h16* __restrict__ Bl,
    const float* __restrict__ E, const float* __restrict__ bcv,
    const float* __restrict__ Wx, const float* __restrict__ x,
    const float* __restrict__ X1t, const float* __restrict__ X2t,
    const float* __restrict__ ubuf, h16* __restrict__ HRh, h16* __restrict__ HRl,
    float* __restrict__ out, int lt) {
  const int R0 = blockIdx.x * 32;
  const int bl = R0 >> 11, n0 = R0 & 2047;
  __shared__ __align__(16) h16 sAh[32 * LP], sAl[32 * LP];
  __shared__ __align__(16) h16 sBh[64 * LP], sBl[64 * LP];
  const int tid = threadIdx.x, lane = tid & 63, w = tid >> 6;
  v4f acc[2] = {};
  const int asr = tid >> 3, asc = (tid & 7) * 8;   // A: 32 rows x 8 f32
  const int bsr = tid >> 2, bso = (tid & 3) * 16;  // B: 64 rows x 16 h16
  const float* erow = E + (size_t)(n0 + asr) * 10;
  const h16* bhrow = Bh + (size_t)bsr * 1920 + bso;
  const h16* blrow = Bl + (size_t)bsr * 1920 + bso;
  v8h ah, al, pbh[2], pbl[2];
  auto load_t = [&](int t, int d, int jb) {
    const float e = erow[d];
    const float* src = (jb == 0)
        ? (RHs + (size_t)bl * 1572864 + (size_t)(n0 + asr) * 64 + asc)
        : (xs + (size_t)(R0 + asr) * 192 + jb * 64 + asc);
    v4f a0 = *(const v4f*)src;
    v4f a1 = *(const v4f*)(src + 4);
#pragma unroll
    for (int q = 0; q < 4; ++q) {
      float v = a0[q] * e; h16 hh = (h16)v; ah[q] = hh; al[q] = (h16)(v - (float)hh);
      v = a1[q] * e; hh = (h16)v; ah[4 + q] = hh; al[4 + q] = (h16)(v - (float)hh);
    }
#pragma unroll
    for (int c = 0; c < 2; ++c) {
      pbh[c] = *(const v8h*)(bhrow + t * 64 + c * 8);
      pbl[c] = *(const v8h*)(blrow + t * 64 + c * 8);
    }
  };
  load_t(0, 0, 0);
  int d = 0, jb = 0;
  for (int t = 0; t < 30; ++t) {
    __syncthreads();
    *(v8h*)(sAh + asr * LP + asc) = ah;
    *(v8h*)(sAl + asr * LP + asc) = al;
#pragma unroll
    for (int c = 0; c < 2; ++c) {
      *(v8h*)(sBh + bsr * LP + bso + c * 8) = pbh[c];
      *(v8h*)(sBl + bsr * LP + bso + c * 8) = pbl[c];
    }
    __syncthreads();
    int dn = d, jn = jb + 1;
    if (jn == 3) { jn = 0; ++dn; }
    if (t < 29) load_t(t + 1, dn, jn);
#pragma unroll
    for (int kk = 0; kk < 2; ++kk) {
      const int ko = kk * 32 + (lane >> 4) * 8;
      const int rs = lane & 15;
      v8h Ah0 = *(const v8h*)(sAh + rs * LP + ko);
      v8h Ah1 = *(const v8h*)(sAh + (16 + rs) * LP + ko);
      v8h Al0 = *(const v8h*)(sAl + rs * LP + ko);
      v8h Al1 = *(const v8h*)(sAl + (16 + rs) * LP + ko);
      v8h Bh0 = *(const v8h*)(sBh + (w * 16 + rs) * LP + ko);
      v8h Bl0 = *(const v8h*)(sBl + (w * 16 + rs) * LP + ko);
      acc[0] = MFMA16(Ah0, Bh0, acc[0]);
      acc[1] = MFMA16(Ah1, Bh0, acc[1]);
      acc[0] = MFMA16(Al0, Bh0, acc[0]);
      acc[1] = MFMA16(Al1, Bh0, acc[1]);
      acc[0] = MFMA16(Ah0, Bl0, acc[0]);
      acc[1] = MFMA16(Ah1, Bl0, acc[1]);
      acc[0] = MFMA16(Al0, Bl0, acc[0]);
      acc[1] = MFMA16(Al1, Bl0, acc[1]);
    }
    d = dn; jb = jn;
  }
  const int l15 = lane & 15, l4 = (lane >> 4) * 4;
  const size_t xbase = ((size_t)(bl * 12 + lt)) * NN;
  const size_t c1 = ((size_t)(lt * 16 + bl)) * 2;
  const int o = w * 16 + l15;
#pragma unroll
  for (int mi = 0; mi < 2; ++mi) {
    float hnv[4];
#pragma unroll
    for (int r = 0; r < 4; ++r) {
      const int Rl = mi * 16 + l4 + r;
      const int n = n0 + Rl;
      const size_t R = (size_t)R0 + Rl;
      const float x0a = x[(xbase + n) * 2 + 0];
      const float x0b = x[(xbase + n) * 2 + 1];
      const float x1a = X1t[c1 * NN + n];
      const float x1b = X1t[(c1 + 1) * NN + n];
      const float x2a = X2t[c1 * NN + n];
      const float x2b = X2t[(c1 + 1) * NN + n];
      const float* wx = Wx + (size_t)n * 384;
      float pre = acc[mi][r] + bcv[(size_t)n * 64 + o]
                + x0a * wx[o]       + x0b * wx[64 + o]
                + x1a * wx[128 + o] + x1b * wx[192 + o]
                + x2a * wx[256 + o] + x2b * wx[320 + o];
      const float cv = tanhf(pre);
      const float u = ubuf[R * 64 + o];
      const float hold = xs[R * 192 + o];
      const float hn = u * hold + (1.f - u) * cv;
      hnv[r] = hn;
      xs[R * 192 + o] = hn;
      out[(xbase + n) * 64 + o] = hn;
    }
    const int nb = n0 + mi * 16 + l4;
    v4h ph, pl;
#pragma unroll
    for (int r = 0; r < 4; ++r) {
      h16 hh = (h16)hnv[r];
      ph[r] = hh;
      pl[r] = (h16)(hnv[r] - (float)hh);
    }
    *(v4h*)(HRh + (size_t)(bl * 64 + o) * 2048 + nb) = ph;
    *(v4h*)(HRl + (size_t)(bl * 64 + o) * 2048 + nb) = pl;
  }
}

// ---------------- h_n gather: xs slot0 -> out (overwrites ubuf region, last) ----------------
__global__ void hn_gather_k(const float* __restrict__ xs, float* __restrict__ dst) {
  int i = blockIdx.x * 256 + threadIdx.x;   // 2,097,152
  dst[i] = xs[(size_t)(i >> 6) * 192 + (i & 63)];
}

// ---------------- launch ----------------
extern "C" void kernel_launch(void* const* d_in, const int* in_sizes, int n_in,
                              void* d_out, int out_size, void* d_ws, size_t ws_size,
                              hipStream_t stream) {
  float* out = (float*)d_out;

  const bool in_ok = (n_in == 7) &&
      in_sizes[0] == 786432 && in_sizes[1] == 20480 && in_sizes[2] == 4194304 &&
      in_sizes[3] == 253440 && in_sizes[4] == 1280 &&
      in_sizes[5] == 126720 && in_sizes[6] == 640 && out_size == 27262976;
  if (!in_ok) {
    fill_k<<<(out_size + 255) / 256, 256, 0, stream>>>(out, 77.0f, (size_t)out_size);
    return;
  }
  constexpr size_t NEED = 85884928;
  if (ws_size < NEED) {
    fill_k<<<106496, 256, 0, stream>>>(out, 42.0f, 27262976);
    return;
  }

  const float* x   = (const float*)d_in[0];
  const float* E   = (const float*)d_in[1];
  const float* A   = (const float*)d_in[2];
  const float* Wgp = (const float*)d_in[3];
  const float* bgp = (const float*)d_in[4];
  const float* Wcp = (const float*)d_in[5];
  const float* bcp = (const float*)d_in[6];

  char* p = (char*)d_ws;
  auto carve = [&](size_t bytes) { char* r = p; p += bytes; return r; };
  // shared
  h16*   ABh  = (h16*)carve(16777216);   // [A*2048 ; A2half] split hi [4096][2048]
  h16*   ABl  = (h16*)carve(16777216);
  float* X1t  = (float*)carve(3145728);  // A@x   [384][2048] fp32
  float* X2t  = (float*)carve(3145728);  // A@(A@x)
  h16*   WgTh = (h16*)carve(491520);     // folded gate W, transposed split [128][1920]
  h16*   WgTl = (h16*)carve(491520);
  h16*   WcTh = (h16*)carve(245760);     // [64][1920]
  h16*   WcTl = (h16*)carve(245760);
  float* WxG  = (float*)carve(6291456);  // [2048][6][128]
  float* WxC  = (float*)carve(3145728);  // [2048][6][64]
  float* bgv  = (float*)carve(1048576);
  float* bcv  = (float*)carve(524288);
  // loop scratch -> total exactly 85,884,928
  float* xs   = (float*)carve(25165824); // [32768][192] fp32: [h | y1 | y2]
  h16*   HRh  = (h16*)carve(4194304);    // h / rh split, feature-major [1024][2048]
  h16*   HRl  = (h16*)carve(4194304);
  // rh fp32 lives in d_out's lt=11 slices (dead until mcand@lt=11 overwrites in place)
  float* RHs  = out + 1441792;           // base = 11*131072; +bl*1572864 + n*64 + o
  // u gate lives in d_out's h_n region (dead until hn_gather at the very end)
  float* ubuf = out + 25165824;          // 8,388,608 B
  // prep-phase aliases inside xs (dead before the loop memset)
  h16* AsTh = (h16*)xs;                               // 8,388,608
  h16* AsTl = (h16*)((char*)xs + 8388608);            // 8,388,608
  h16* X0h  = (h16*)((char*)xs + 16777216);           // 1,572,864
  h16* X0l  = (h16*)((char*)xs + 18350080);
  h16* X1h  = (h16*)((char*)xs + 19922944);
  h16* X1l  = (h16*)((char*)xs + 21495808);

  prep_Asplit_k<<<16384, 256, 0, stream>>>(A, ABh, ABl);
  prep_AsTsplit_k<<<16384, 256, 0, stream>>>(A, AsTh, AsTl);
  prep_wts_k<128><<<960, 256, 0, stream>>>(Wgp, WgTh, WgTl);
  prep_wts_k<64><<<480, 256, 0, stream>>>(Wcp, WcTh, WcTl);
  prep_wx_k<128><<<6144, 256, 0, stream>>>(E, Wgp, WxG);
  prep_wx_k<64><<<3072, 256, 0, stream>>>(E, Wcp, WxC);
  prep_b_k<128><<<1024, 256, 0, stream>>>(E, bgp, bgv);
  prep_b_k<64><<<512, 256, 0, stream>>>(E, bcp, bcv);
  // A2half = INV_N * As@As  -> AB rows 2048..4095 (split pair)
  sgemm_k<2><<<dim3(64, 32), 256, 0, stream>>>(ABh, ABl, AsTh, AsTl,
                                               nullptr, ABh + 4194304, ABl + 4194304,
                                               nullptr, 0);
  // x-path (chained, unchanged arithmetic)
  prep_x0split_k<<<3072, 256, 0, stream>>>(x, X0h, X0l);
  sgemm_k<3><<<dim3(12, 32), 256, 0, stream>>>(X0h, X0l, ABh, ABl, X1t, X1h, X1l, nullptr, 0);
  sgemm_k<1><<<dim3(12, 32), 256, 0, stream>>>(X1h, X1l, ABh, ABl, X2t, nullptr, nullptr, nullptr, 0);

  hipMemsetAsync(xs, 0, 25165824, stream);
  hipMemsetAsync(HRh, 0, 4194304, stream);
  hipMemsetAsync(HRl, 0, 4194304, stream);
  for (int lt = 0; lt < 12; ++lt) {
    // stacked conv: y1 (cols 0-2047) and y2 (cols 2048-4095) in one dispatch
    sgemm_k<4><<<dim3(32, 64), 256, 0, stream>>>(HRh, HRl, ABh, ABl,
                                                 nullptr, nullptr, nullptr, xs, 64);
    mgate_k<<<dim3(1024, 2), 256, 0, stream>>>(xs, WgTh, WgTl, E, bgv, WxG, x, X1t, X2t,
                                               RHs, ubuf, HRh, HRl, lt);
    sgemm_k<4><<<dim3(32, 64), 256, 0, stream>>>(HRh, HRl, ABh, ABl,
                                                 nullptr, nullptr, nullptr, xs, 64);
    mcand_k<<<1024, 256, 0, stream>>>(xs, RHs, WcTh, WcTl, E, bcv, WxC, x, X1t, X2t,
                                      ubuf, HRh, HRl, out, lt);
  }
  hn_gather_k<<<8192, 256, 0, stream>>>(xs, out + 25165824);
}

// Round 14
// 3808.329 us; speedup vs baseline: 16.9800x; 1.1361x over previous
//
#include <hip/hip_runtime.h>
#include <cstdint>
#include <cstddef>

typedef _Float16 h16;
typedef h16 v8h __attribute__((ext_vector_type(8)));
typedef h16 v4h __attribute__((ext_vector_type(4)));
typedef float v4f __attribute__((ext_vector_type(4)));

constexpr int NN = 2048;
constexpr float INV_N = 1.0f / 2048.0f;
constexpr int LP = 72;  // LDS row stride in halves (64 + 8 pad)

#define MFMA16(a, b, c) __builtin_amdgcn_mfma_f32_16x16x32_f16((a), (b), (c), 0, 0, 0)

// ---------------- diagnostic fill ----------------
__global__ void fill_k(float* __restrict__ o, float v, size_t ntot) {
  size_t i = (size_t)blockIdx.x * 256 + threadIdx.x;
  if (i < ntot) o[i] = v;
}

// ---------------- prep kernels ----------------

__global__ void prep_Asplit_k(const float* __restrict__ A,
                              h16* __restrict__ hi, h16* __restrict__ lo) {
  int tid = blockIdx.x * 256 + threadIdx.x;   // 4M
  float v = A[tid] * 2048.0f;
  h16 h = (h16)v;
  hi[tid] = h;
  lo[tid] = (h16)(v - (float)h);
}

// AsT[j][t] = A[t][j]*2048, split (coalesced writes; strided reads once, L3-absorbed)
__global__ void prep_AsTsplit_k(const float* __restrict__ A,
                                h16* __restrict__ hi, h16* __restrict__ lo) {
  int tid = blockIdx.x * 256 + threadIdx.x;   // 4M
  int t = tid & 2047, j = tid >> 11;
  float v = A[(size_t)t * NN + j] * 2048.0f;
  h16 h = (h16)v;
  hi[(size_t)j * NN + t] = h;
  lo[(size_t)j * NN + t] = (h16)(v - (float)h);
}

__global__ void prep_x0split_k(const float* __restrict__ x,
                               h16* __restrict__ hi, h16* __restrict__ lo) {
  int tid = blockIdx.x * 256 + threadIdx.x;   // 384*2048
  int n = tid & 2047, c = tid >> 11;
  int ii = c & 1, b = (c >> 1) & 15, lt = c >> 5;
  float v = x[(((size_t)(b * 12 + lt)) * NN + n) * 2 + ii];
  h16 h = (h16)v;
  hi[tid] = h;
  lo[tid] = (h16)(v - (float)h);
}

template<int CO>
__global__ void prep_wts_k(const float* __restrict__ Wp,
                           h16* __restrict__ WTh, h16* __restrict__ WTl) {
  int tid = blockIdx.x * 256 + threadIdx.x;   // CO*1920
  int kk = tid % 1920, o = tid / 1920;
  int d = kk / 192, rem = kk - d * 192;
  int jb = rem >> 6, i = rem & 63;
  float v;
  if (jb == 0)
    v = Wp[((size_t)((d * 3 + 0) * 66 + i)) * CO + o] -
        Wp[((size_t)((d * 3 + 2) * 66 + i)) * CO + o];
  else if (jb == 1)
    v = Wp[((size_t)((d * 3 + 1) * 66 + i)) * CO + o];
  else
    v = 2.f * Wp[((size_t)((d * 3 + 2) * 66 + i)) * CO + o];
  h16 h = (h16)v;
  WTh[tid] = h;
  WTl[tid] = (h16)(v - (float)h);
}

template<int CO>
__global__ void prep_wx_k(const float* __restrict__ E, const float* __restrict__ Wp,
                          float* __restrict__ Wx) {
  int tid = blockIdx.x * 256 + threadIdx.x;   // 2048*6*CO
  int o = tid & (CO - 1), t6 = (tid / CO) % 6, n = tid / (6 * CO);
  int k = t6 >> 1, ii = t6 & 1;
  float s = 0.f;
  for (int d = 0; d < 10; ++d) {
    float p0 = Wp[((size_t)((d * 3 + 0) * 66 + 64 + ii)) * CO + o];
    float p1 = Wp[((size_t)((d * 3 + 1) * 66 + 64 + ii)) * CO + o];
    float p2 = Wp[((size_t)((d * 3 + 2) * 66 + 64 + ii)) * CO + o];
    float v = (k == 0) ? (p0 - p2) : (k == 1 ? p1 : 2.f * p2);
    s += E[n * 10 + d] * v;
  }
  Wx[tid] = s;
}

template<int CO>
__global__ void prep_b_k(const float* __restrict__ E, const float* __restrict__ bp,
                         float* __restrict__ bv) {
  int tid = blockIdx.x * 256 + threadIdx.x;   // 2048*CO
  int o = tid & (CO - 1), n = tid / CO;
  float s = 0.f;
  for (int d = 0; d < 10; ++d) s += E[n * 10 + d] * bp[d * CO + o];
  bv[tid] = s;
}

// ---------------- split-fp16 MFMA SpMM, BM=64/BN=64, 256 thr (4 waves 2x2, wave 32x32) ----------------
// out[c][n] = INV_N * sum_m (Ih+Il)[c][m] * (Bh+Bl)[n][m]   (3-product split, order hh->lh->hl)
// OM bit0: oF fp32 feature; bit1: oH/oL split feature; bit2: xs scatter
// (stacked-aware: col n>=2048 -> slot xoff+64).
template<int OM>
__global__ __launch_bounds__(256, 4) void sgemm_k(
    const h16* __restrict__ Ih, const h16* __restrict__ Il,
    const h16* __restrict__ Bh, const h16* __restrict__ Bl,
    float* __restrict__ oF, h16* __restrict__ oH, h16* __restrict__ oL,
    float* __restrict__ xsv, int xoff) {
  const int m0 = blockIdx.x * 64, n0 = blockIdx.y * 64;
  __shared__ __align__(16) h16 sAh[64 * LP], sAl[64 * LP];
  __shared__ __align__(16) h16 sBh[64 * LP], sBl[64 * LP];
  const int tid = threadIdx.x, lane = tid & 63, w = tid >> 6;
  const int wm = w >> 1, wn = w & 1;
  v4f acc[2][2] = {};
  const int sr = tid >> 2, sc = (tid & 3) * 16;   // stage: 64 rows x 16 halves/thread
  v8h rah0 = *(const v8h*)(Ih + (size_t)(m0 + sr) * NN + sc);
  v8h rah1 = *(const v8h*)(Ih + (size_t)(m0 + sr) * NN + sc + 8);
  v8h ral0 = *(const v8h*)(Il + (size_t)(m0 + sr) * NN + sc);
  v8h ral1 = *(const v8h*)(Il + (size_t)(m0 + sr) * NN + sc + 8);
  v8h rbh0 = *(const v8h*)(Bh + (size_t)(n0 + sr) * NN + sc);
  v8h rbh1 = *(const v8h*)(Bh + (size_t)(n0 + sr) * NN + sc + 8);
  v8h rbl0 = *(const v8h*)(Bl + (size_t)(n0 + sr) * NN + sc);
  v8h rbl1 = *(const v8h*)(Bl + (size_t)(n0 + sr) * NN + sc + 8);
  for (int kt = 0; kt < NN; kt += 64) {
    __syncthreads();
    *(v8h*)(sAh + sr * LP + sc) = rah0;
    *(v8h*)(sAh + sr * LP + sc + 8) = rah1;
    *(v8h*)(sAl + sr * LP + sc) = ral0;
    *(v8h*)(sAl + sr * LP + sc + 8) = ral1;
    *(v8h*)(sBh + sr * LP + sc) = rbh0;
    *(v8h*)(sBh + sr * LP + sc + 8) = rbh1;
    *(v8h*)(sBl + sr * LP + sc) = rbl0;
    *(v8h*)(sBl + sr * LP + sc + 8) = rbl1;
    __syncthreads();
    if (kt + 64 < NN) {
      const int k2 = kt + 64 + sc;
      rah0 = *(const v8h*)(Ih + (size_t)(m0 + sr) * NN + k2);
      rah1 = *(const v8h*)(Ih + (size_t)(m0 + sr) * NN + k2 + 8);
      ral0 = *(const v8h*)(Il + (size_t)(m0 + sr) * NN + k2);
      ral1 = *(const v8h*)(Il + (size_t)(m0 + sr) * NN + k2 + 8);
      rbh0 = *(const v8h*)(Bh + (size_t)(n0 + sr) * NN + k2);
      rbh1 = *(const v8h*)(Bh + (size_t)(n0 + sr) * NN + k2 + 8);
      rbl0 = *(const v8h*)(Bl + (size_t)(n0 + sr) * NN + k2);
      rbl1 = *(const v8h*)(Bl + (size_t)(n0 + sr) * NN + k2 + 8);
    }
#pragma unroll
    for (int kk = 0; kk < 2; ++kk) {
      const int ko = kk * 32 + (lane >> 4) * 8;
      const int rs = lane & 15;
      v8h Ah0 = *(const v8h*)(sAh + (wm * 32 + rs) * LP + ko);
      v8h Ah1 = *(const v8h*)(sAh + (wm * 32 + 16 + rs) * LP + ko);
      v8h Al0 = *(const v8h*)(sAl + (wm * 32 + rs) * LP + ko);
      v8h Al1 = *(const v8h*)(sAl + (wm * 32 + 16 + rs) * LP + ko);
      v8h Bh0 = *(const v8h*)(sBh + (wn * 32 + rs) * LP + ko);
      v8h Bh1 = *(const v8h*)(sBh + (wn * 32 + 16 + rs) * LP + ko);
      v8h Bl0 = *(const v8h*)(sBl + (wn * 32 + rs) * LP + ko);
      v8h Bl1 = *(const v8h*)(sBl + (wn * 32 + 16 + rs) * LP + ko);
      acc[0][0] = MFMA16(Ah0, Bh0, acc[0][0]);
      acc[0][1] = MFMA16(Ah0, Bh1, acc[0][1]);
      acc[1][0] = MFMA16(Ah1, Bh0, acc[1][0]);
      acc[1][1] = MFMA16(Ah1, Bh1, acc[1][1]);
      acc[0][0] = MFMA16(Al0, Bh0, acc[0][0]);
      acc[0][1] = MFMA16(Al0, Bh1, acc[0][1]);
      acc[1][0] = MFMA16(Al1, Bh0, acc[1][0]);
      acc[1][1] = MFMA16(Al1, Bh1, acc[1][1]);
      acc[0][0] = MFMA16(Ah0, Bl0, acc[0][0]);
      acc[0][1] = MFMA16(Ah0, Bl1, acc[0][1]);
      acc[1][0] = MFMA16(Ah1, Bl0, acc[1][0]);
      acc[1][1] = MFMA16(Ah1, Bl1, acc[1][1]);
    }
  }
  const int l15 = lane & 15, l4 = (lane >> 4) * 4;
#pragma unroll
  for (int ni = 0; ni < 2; ++ni) {
    const int n = n0 + wn * 32 + ni * 16 + l15;
#pragma unroll
    for (int mi = 0; mi < 2; ++mi) {
      const int cb = m0 + wm * 32 + mi * 16 + l4;
      float vv[4];
#pragma unroll
      for (int r = 0; r < 4; ++r) {
        vv[r] = acc[mi][ni][r] * INV_N;
        if constexpr (OM & 1) oF[(size_t)(cb + r) * NN + n] = vv[r];
        if constexpr (OM & 2) {
          h16 h = (h16)vv[r];
          oH[(size_t)(cb + r) * NN + n] = h;
          oL[(size_t)(cb + r) * NN + n] = (h16)(vv[r] - (float)h);
        }
      }
      if constexpr (OM & 4) {
        const int n2 = n & 2047;
        const int xo = xoff + ((n >> 11) << 6);
        v4f pv = {vv[0], vv[1], vv[2], vv[3]};
        *(v4f*)(xsv + ((size_t)(cb >> 6) * 2048 + n2) * 192 + xo + (cb & 63)) = pv;
      }
    }
  }
}

// ---------------- MFMA gate: BM=32, BN=64 via gridDim.y o-family split (r13 verbatim) ----------------
// gy==0: o in [0,64) -> r-gate, rh writes.  gy==1: o in [64,128) -> u-gate.
__global__ __launch_bounds__(256) void mgate_k(
    const float* __restrict__ xs, const h16* __restrict__ Bh, const h16* __restrict__ Bl,
    const float* __restrict__ E, const float* __restrict__ bgv,
    const float* __restrict__ Wx, const float* __restrict__ x,
    const float* __restrict__ X1t, const float* __restrict__ X2t,
    float* __restrict__ RHs, float* __restrict__ ubuf,
    h16* __restrict__ HRh, h16* __restrict__ HRl, int lt) {
  const int R0 = blockIdx.x * 32;
  const int gy = blockIdx.y, ob = gy * 64;
  const int bl = R0 >> 11, n0 = R0 & 2047;
  __shared__ __align__(16) h16 sAh[32 * LP], sAl[32 * LP];
  __shared__ __align__(16) h16 sBh[64 * LP], sBl[64 * LP];
  const int tid = threadIdx.x, lane = tid & 63, w = tid >> 6;
  v4f acc[2] = {};
  const int asr = tid >> 3, asc = (tid & 7) * 8;   // A: 32 rows x 8 f32
  const int bsr = tid >> 2, bso = (tid & 3) * 16;  // B: 64 rows x 16 h16
  const float* arow = xs + (size_t)(R0 + asr) * 192 + asc;
  const float* erow = E + (size_t)(n0 + asr) * 10;
  const h16* bhrow = Bh + (size_t)(ob + bsr) * 1920 + bso;
  const h16* blrow = Bl + (size_t)(ob + bsr) * 1920 + bso;
  v8h ah, al, pbh[2], pbl[2];
  auto load_t = [&](int t, int d, int jb) {
    const float e = erow[d];
    v4f a0 = *(const v4f*)(arow + jb * 64);
    v4f a1 = *(const v4f*)(arow + jb * 64 + 4);
#pragma unroll
    for (int q = 0; q < 4; ++q) {
      float v = a0[q] * e; h16 hh = (h16)v; ah[q] = hh; al[q] = (h16)(v - (float)hh);
      v = a1[q] * e; hh = (h16)v; ah[4 + q] = hh; al[4 + q] = (h16)(v - (float)hh);
    }
#pragma unroll
    for (int c = 0; c < 2; ++c) {
      pbh[c] = *(const v8h*)(bhrow + t * 64 + c * 8);
      pbl[c] = *(const v8h*)(blrow + t * 64 + c * 8);
    }
  };
  load_t(0, 0, 0);
  int d = 0, jb = 0;
  for (int t = 0; t < 30; ++t) {
    __syncthreads();
    *(v8h*)(sAh + asr * LP + asc) = ah;
    *(v8h*)(sAl + asr * LP + asc) = al;
#pragma unroll
    for (int c = 0; c < 2; ++c) {
      *(v8h*)(sBh + bsr * LP + bso + c * 8) = pbh[c];
      *(v8h*)(sBl + bsr * LP + bso + c * 8) = pbl[c];
    }
    __syncthreads();
    int dn = d, jn = jb + 1;
    if (jn == 3) { jn = 0; ++dn; }
    if (t < 29) load_t(t + 1, dn, jn);
#pragma unroll
    for (int kk = 0; kk < 2; ++kk) {
      const int ko = kk * 32 + (lane >> 4) * 8;
      const int rs = lane & 15;
      v8h Ah0 = *(const v8h*)(sAh + rs * LP + ko);
      v8h Ah1 = *(const v8h*)(sAh + (16 + rs) * LP + ko);
      v8h Al0 = *(const v8h*)(sAl + rs * LP + ko);
      v8h Al1 = *(const v8h*)(sAl + (16 + rs) * LP + ko);
      v8h Bh0 = *(const v8h*)(sBh + (w * 16 + rs) * LP + ko);
      v8h Bl0 = *(const v8h*)(sBl + (w * 16 + rs) * LP + ko);
      acc[0] = MFMA16(Ah0, Bh0, acc[0]);
      acc[1] = MFMA16(Ah1, Bh0, acc[1]);
      acc[0] = MFMA16(Al0, Bh0, acc[0]);
      acc[1] = MFMA16(Al1, Bh0, acc[1]);
      acc[0] = MFMA16(Ah0, Bl0, acc[0]);
      acc[1] = MFMA16(Ah1, Bl0, acc[1]);
      acc[0] = MFMA16(Al0, Bl0, acc[0]);
      acc[1] = MFMA16(Al1, Bl0, acc[1]);
    }
    d = dn; jb = jn;
  }
  const int l15 = lane & 15, l4 = (lane >> 4) * 4;
  const size_t xbase = ((size_t)(bl * 12 + lt)) * NN;
  const size_t c1 = ((size_t)(lt * 16 + bl)) * 2;
  const int o = ob + w * 16 + l15;
#pragma unroll
  for (int mi = 0; mi < 2; ++mi) {
    float rhv[4];
#pragma unroll
    for (int r = 0; r < 4; ++r) {
      const int Rl = mi * 16 + l4 + r;
      const int n = n0 + Rl;
      const size_t R = (size_t)R0 + Rl;
      const float x0a = x[(xbase + n) * 2 + 0];
      const float x0b = x[(xbase + n) * 2 + 1];
      const float x1a = X1t[c1 * NN + n];
      const float x1b = X1t[(c1 + 1) * NN + n];
      const float x2a = X2t[c1 * NN + n];
      const float x2b = X2t[(c1 + 1) * NN + n];
      const float* wx = Wx + (size_t)n * 768;
      float pre = acc[mi][r] + bgv[(size_t)n * 128 + o]
                + x0a * wx[o]       + x0b * wx[128 + o]
                + x1a * wx[256 + o] + x1b * wx[384 + o]
                + x2a * wx[512 + o] + x2b * wx[640 + o];
      const float g = 1.f / (1.f + expf(-pre));
      if (gy == 0) {
        const float rh = g * xs[R * 192 + o];
        RHs[(size_t)bl * 1572864 + (size_t)n * 64 + o] = rh;
        rhv[r] = rh;
      } else {
        ubuf[R * 64 + (o - 64)] = g;
      }
    }
    if (gy == 0) {
      const int nb = n0 + mi * 16 + l4;
      v4h ph, pl;
#pragma unroll
      for (int r = 0; r < 4; ++r) {
        h16 hh = (h16)rhv[r];
        ph[r] = hh;
        pl[r] = (h16)(rhv[r] - (float)hh);
      }
      *(v4h*)(HRh + (size_t)(bl * 64 + o) * 2048 + nb) = ph;
      *(v4h*)(HRl + (size_t)(bl * 64 + o) * 2048 + nb) = pl;
    }
  }
}

// ---------------- MFMA cand + GRU update: BM=32/BN=64 (r13 verbatim) ----------------
__global__ __launch_bounds__(256) void mcand_k(
    float* __restrict__ xs, const float* __restrict__ RHs,
    const h16* __restrict__ Bh, const h16* __restrict__ Bl,
    const float* __restrict__ E, const float* __restrict__ bcv,
    const float* __restrict__ Wx, const float* __restrict__ x,
    const float* __restrict__ X1t, const float* __restrict__ X2t,
    const float* __restrict__ ubuf, h16* __restrict__ HRh, h16* __restrict__ HRl,
    float* __restrict__ out, int lt) {
  const int R0 = blockIdx.x * 32;
  const int bl = R0 >> 11, n0 = R0 & 2047;
  __shared__ __align__(16) h16 sAh[32 * LP], sAl[32 * LP];
  __shared__ __align__(16) h16 sBh[64 * LP], sBl[64 * LP];
  const int tid = threadIdx.x, lane = tid & 63, w = tid >> 6;
  v4f acc[2] = {};
  const int asr = tid >> 3, asc = (tid & 7) * 8;   // A: 32 rows x 8 f32
  const int bsr = tid >> 2, bso = (tid & 3) * 16;  // B: 64 rows x 16 h16
  const float* erow = E + (size_t)(n0 + asr) * 10;
  const h16* bhrow = Bh + (size_t)bsr * 1920 + bso;
  const h16* blrow = Bl + (size_t)bsr * 1920 + bso;
  v8h ah, al, pbh[2], pbl[2];
  auto load_t = [&](int t, int d, int jb) {
    const float e = erow[d];
    const float* src = (jb == 0)
        ? (RHs + (size_t)bl * 1572864 + (size_t)(n0 + asr) * 64 + asc)
        : (xs + (size_t)(R0 + asr) * 192 + jb * 64 + asc);
    v4f a0 = *(const v4f*)src;
    v4f a1 = *(const v4f*)(src + 4);
#pragma unroll
    for (int q = 0; q < 4; ++q) {
      float v = a0[q] * e; h16 hh = (h16)v; ah[q] = hh; al[q] = (h16)(v - (float)hh);
      v = a1[q] * e; hh = (h16)v; ah[4 + q] = hh; al[4 + q] = (h16)(v - (float)hh);
    }
#pragma unroll
    for (int c = 0; c < 2; ++c) {
      pbh[c] = *(const v8h*)(bhrow + t * 64 + c * 8);
      pbl[c] = *(const v8h*)(blrow + t * 64 + c * 8);
    }
  };
  load_t(0, 0, 0);
  int d = 0, jb = 0;
  for (int t = 0; t < 30; ++t) {
    __syncthreads();
    *(v8h*)(sAh + asr * LP + asc) = ah;
    *(v8h*)(sAl + asr * LP + asc) = al;
#pragma unroll
    for (int c = 0; c < 2; ++c) {
      *(v8h*)(sBh + bsr * LP + bso + c * 8) = pbh[c];
      *(v8h*)(sBl + bsr * LP + bso + c * 8) = pbl[c];
    }
    __syncthreads();
    int dn = d, jn = jb + 1;
    if (jn == 3) { jn = 0; ++dn; }
    if (t < 29) load_t(t + 1, dn, jn);
#pragma unroll
    for (int kk = 0; kk < 2; ++kk) {
      const int ko = kk * 32 + (lane >> 4) * 8;
      const int rs = lane & 15;
      v8h Ah0 = *(const v8h*)(sAh + rs * LP + ko);
      v8h Ah1 = *(const v8h*)(sAh + (16 + rs) * LP + ko);
      v8h Al0 = *(const v8h*)(sAl + rs * LP + ko);
      v8h Al1 = *(const v8h*)(sAl + (16 + rs) * LP + ko);
      v8h Bh0 = *(const v8h*)(sBh + (w * 16 + rs) * LP + ko);
      v8h Bl0 = *(const v8h*)(sBl + (w * 16 + rs) * LP + ko);
      acc[0] = MFMA16(Ah0, Bh0, acc[0]);
      acc[1] = MFMA16(Ah1, Bh0, acc[1]);
      acc[0] = MFMA16(Al0, Bh0, acc[0]);
      acc[1] = MFMA16(Al1, Bh0, acc[1]);
      acc[0] = MFMA16(Ah0, Bl0, acc[0]);
      acc[1] = MFMA16(Ah1, Bl0, acc[1]);
      acc[0] = MFMA16(Al0, Bl0, acc[0]);
      acc[1] = MFMA16(Al1, Bl0, acc[1]);
    }
    d = dn; jb = jn;
  }
  const int l15 = lane & 15, l4 = (lane >> 4) * 4;
  const size_t xbase = ((size_t)(bl * 12 + lt)) * NN;
  const size_t c1 = ((size_t)(lt * 16 + bl)) * 2;
  const int o = w * 16 + l15;
#pragma unroll
  for (int mi = 0; mi < 2; ++mi) {
    float hnv[4];
#pragma unroll
    for (int r = 0; r < 4; ++r) {
      const int Rl = mi * 16 + l4 + r;
      const int n = n0 + Rl;
      const size_t R = (size_t)R0 + Rl;
      const float x0a = x[(xbase + n) * 2 + 0];
      const float x0b = x[(xbase + n) * 2 + 1];
      const float x1a = X1t[c1 * NN + n];
      const float x1b = X1t[(c1 + 1) * NN + n];
      const float x2a = X2t[c1 * NN + n];
      const float x2b = X2t[(c1 + 1) * NN + n];
      const float* wx = Wx + (size_t)n * 384;
      float pre = acc[mi][r] + bcv[(size_t)n * 64 + o]
                + x0a * wx[o]       + x0b * wx[64 + o]
                + x1a * wx[128 + o] + x1b * wx[192 + o]
                + x2a * wx[256 + o] + x2b * wx[320 + o];
      const float cv = tanhf(pre);
      const float u = ubuf[R * 64 + o];
      const float hold = xs[R * 192 + o];
      const float hn = u * hold + (1.f - u) * cv;
      hnv[r] = hn;
      xs[R * 192 + o] = hn;
      out[(xbase + n) * 64 + o] = hn;
    }
    const int nb = n0 + mi * 16 + l4;
    v4h ph, pl;
#pragma unroll
    for (int r = 0; r < 4; ++r) {
      h16 hh = (h16)hnv[r];
      ph[r] = hh;
      pl[r] = (h16)(hnv[r] - (float)hh);
    }
    *(v4h*)(HRh + (size_t)(bl * 64 + o) * 2048 + nb) = ph;
    *(v4h*)(HRl + (size_t)(bl * 64 + o) * 2048 + nb) = pl;
  }
}

// ---------------- h_n gather: xs slot0 -> out (overwrites ubuf region, last) ----------------
__global__ void hn_gather_k(const float* __restrict__ xs, float* __restrict__ dst) {
  int i = blockIdx.x * 256 + threadIdx.x;   // 2,097,152
  dst[i] = xs[(size_t)(i >> 6) * 192 + (i & 63)];
}

// ---------------- launch ----------------
extern "C" void kernel_launch(void* const* d_in, const int* in_sizes, int n_in,
                              void* d_out, int out_size, void* d_ws, size_t ws_size,
                              hipStream_t stream) {
  float* out = (float*)d_out;

  const bool in_ok = (n_in == 7) &&
      in_sizes[0] == 786432 && in_sizes[1] == 20480 && in_sizes[2] == 4194304 &&
      in_sizes[3] == 253440 && in_sizes[4] == 1280 &&
      in_sizes[5] == 126720 && in_sizes[6] == 640 && out_size == 27262976;
  if (!in_ok) {
    fill_k<<<(out_size + 255) / 256, 256, 0, stream>>>(out, 77.0f, (size_t)out_size);
    return;
  }
  constexpr size_t NEED = 85884928;
  if (ws_size < NEED) {
    fill_k<<<106496, 256, 0, stream>>>(out, 42.0f, 27262976);
    return;
  }

  const float* x   = (const float*)d_in[0];
  const float* E   = (const float*)d_in[1];
  const float* A   = (const float*)d_in[2];
  const float* Wgp = (const float*)d_in[3];
  const float* bgp = (const float*)d_in[4];
  const float* Wcp = (const float*)d_in[5];
  const float* bcp = (const float*)d_in[6];

  char* p = (char*)d_ws;
  auto carve = [&](size_t bytes) { char* r = p; p += bytes; return r; };
  // shared
  h16*   ABh  = (h16*)carve(16777216);   // [A*2048 ; A2half] split hi [4096][2048]
  h16*   ABl  = (h16*)carve(16777216);
  float* X1t  = (float*)carve(3145728);  // A@x   [384][2048] fp32
  float* X2t  = (float*)carve(3145728);  // A@(A@x)
  h16*   WgTh = (h16*)carve(491520);     // folded gate W, transposed split [128][1920]
  h16*   WgTl = (h16*)carve(491520);
  h16*   WcTh = (h16*)carve(245760);     // [64][1920]
  h16*   WcTl = (h16*)carve(245760);
  float* WxG  = (float*)carve(6291456);  // [2048][6][128]
  float* WxC  = (float*)carve(3145728);  // [2048][6][64]
  float* bgv  = (float*)carve(1048576);
  float* bcv  = (float*)carve(524288);
  // loop scratch -> total exactly 85,884,928
  float* xs   = (float*)carve(25165824); // [32768][192] fp32: [h | y1 | y2]
  h16*   HRh  = (h16*)carve(4194304);    // h / rh split, feature-major [1024][2048]
  h16*   HRl  = (h16*)carve(4194304);
  // rh fp32 lives in d_out's lt=11 slices (dead until mcand@lt=11 overwrites in place)
  float* RHs  = out + 1441792;           // base = 11*131072; +bl*1572864 + n*64 + o
  // u gate lives in d_out's h_n region (dead until hn_gather at the very end)
  float* ubuf = out + 25165824;          // 8,388,608 B
  // prep-phase aliases inside xs (dead before the loop memset)
  h16* AsTh = (h16*)xs;                               // 8,388,608
  h16* AsTl = (h16*)((char*)xs + 8388608);            // 8,388,608
  h16* X0h  = (h16*)((char*)xs + 16777216);           // 1,572,864
  h16* X0l  = (h16*)((char*)xs + 18350080);
  h16* X1h  = (h16*)((char*)xs + 19922944);
  h16* X1l  = (h16*)((char*)xs + 21495808);

  prep_Asplit_k<<<16384, 256, 0, stream>>>(A, ABh, ABl);
  prep_AsTsplit_k<<<16384, 256, 0, stream>>>(A, AsTh, AsTl);
  prep_wts_k<128><<<960, 256, 0, stream>>>(Wgp, WgTh, WgTl);
  prep_wts_k<64><<<480, 256, 0, stream>>>(Wcp, WcTh, WcTl);
  prep_wx_k<128><<<6144, 256, 0, stream>>>(E, Wgp, WxG);
  prep_wx_k<64><<<3072, 256, 0, stream>>>(E, Wcp, WxC);
  prep_b_k<128><<<1024, 256, 0, stream>>>(E, bgp, bgv);
  prep_b_k<64><<<512, 256, 0, stream>>>(E, bcp, bcv);
  // A2half = INV_N * As@As  -> AB rows 2048..4095 (split pair)
  sgemm_k<2><<<dim3(32, 32), 256, 0, stream>>>(ABh, ABl, AsTh, AsTl,
                                               nullptr, ABh + 4194304, ABl + 4194304,
                                               nullptr, 0);
  // x-path (chained, unchanged arithmetic)
  prep_x0split_k<<<3072, 256, 0, stream>>>(x, X0h, X0l);
  sgemm_k<3><<<dim3(6, 32), 256, 0, stream>>>(X0h, X0l, ABh, ABl, X1t, X1h, X1l, nullptr, 0);
  sgemm_k<1><<<dim3(6, 32), 256, 0, stream>>>(X1h, X1l, ABh, ABl, X2t, nullptr, nullptr, nullptr, 0);

  hipMemsetAsync(xs, 0, 25165824, stream);
  hipMemsetAsync(HRh, 0, 4194304, stream);
  hipMemsetAsync(HRl, 0, 4194304, stream);
  for (int lt = 0; lt < 12; ++lt) {
    // stacked conv: y1 (cols 0-2047) and y2 (cols 2048-4095) in one dispatch
    sgemm_k<4><<<dim3(16, 64), 256, 0, stream>>>(HRh, HRl, ABh, ABl,
                                                 nullptr, nullptr, nullptr, xs, 64);
    mgate_k<<<dim3(1024, 2), 256, 0, stream>>>(xs, WgTh, WgTl, E, bgv, WxG, x, X1t, X2t,
                                               RHs, ubuf, HRh, HRl, lt);
    sgemm_k<4><<<dim3(16, 64), 256, 0, stream>>>(HRh, HRl, ABh, ABl,
                                                 nullptr, nullptr, nullptr, xs, 64);
    mcand_k<<<1024, 256, 0, stream>>>(xs, RHs, WcTh, WcTl, E, bcv, WxC, x, X1t, X2t,
                                      ubuf, HRh, HRl, out, lt);
  }
  hn_gather_k<<<8192, 256, 0, stream>>>(xs, out + 25165824);
}